// Round 8
// baseline (421.334 us; speedup 1.0000x reference)
//
#include <hip/hip_runtime.h>
#include <hip/hip_bf16.h>
#include <math.h>

#define F 128
#define NH 8
#define HD 16

static inline int cdiv(int a, int b) { return (a + b - 1) / b; }

typedef __attribute__((ext_vector_type(8))) short bf16x8;
typedef __attribute__((ext_vector_type(4))) float f32x4;

__device__ __forceinline__ float geluf(float x) {
    return 0.5f * x * (1.f + erff(x * 0.70710678118654752440f));
}

__device__ __forceinline__ short f2bf(float f) {
    __hip_bfloat16 h = __float2bfloat16(f);
    return *reinterpret_cast<short*>(&h);
}

__device__ __forceinline__ float bflo(unsigned int u) { return __uint_as_float(u << 16); }
__device__ __forceinline__ float bfhi(unsigned int u) { return __uint_as_float(u & 0xffff0000u); }
__device__ __forceinline__ float bf2f(short s) {
    return __uint_as_float(((unsigned int)(unsigned short)s) << 16);
}

// ---- weight prep: per layer 10 slots of bf16 [n][k] + 10 f32 bias slots ----
// slot: 0 q(t0) | 1 k-fused e0 | 2 v-fused e0 | 3 k-fused e2 | 4 v-fused e2
//       5 q(t1) | 6 k-fused e1 | 7 v-fused e1 | 8 a(t0) | 9 a(t1)
__device__ __forceinline__ void slot_info(int slot, int& kind, int& wsel, int& e, int& t) {
    switch (slot) {
        case 0: kind = 0; wsel = 0; t = 0; e = 0; break;
        case 1: kind = 1; wsel = 1; t = 0; e = 0; break;
        case 2: kind = 1; wsel = 2; t = 0; e = 0; break;
        case 3: kind = 1; wsel = 1; t = 0; e = 2; break;
        case 4: kind = 1; wsel = 2; t = 0; e = 2; break;
        case 5: kind = 0; wsel = 0; t = 1; e = 0; break;
        case 6: kind = 1; wsel = 1; t = 1; e = 1; break;
        case 7: kind = 1; wsel = 2; t = 1; e = 1; break;
        case 8: kind = 0; wsel = 3; t = 0; e = 0; break;
        default: kind = 0; wsel = 3; t = 1; e = 0; break;
    }
}

__global__ void prep_weights(const float* __restrict__ Wk, const float* __restrict__ bk,
                             const float* __restrict__ Wq, const float* __restrict__ bq,
                             const float* __restrict__ Wv, const float* __restrict__ bv,
                             const float* __restrict__ Wa, const float* __restrict__ ba,
                             const float* __restrict__ arel, const float* __restrict__ mrel,
                             short* __restrict__ Wslots, float* __restrict__ bslots) {
    const int WTOT = 10 * 16384;
    const int layer = blockIdx.y;
    short* Wl = Wslots + (size_t)layer * WTOT;
    float* bl = bslots + (size_t)layer * 10 * 128;
    int idx = blockIdx.x * blockDim.x + threadIdx.x;
    if (idx < WTOT) {
        int slot = idx >> 14, rem = idx & 16383;
        int n = rem >> 7, k = rem & 127;
        int kind, wsel, e, t;
        slot_info(slot, kind, wsel, e, t);
        float out;
        if (kind == 0) {
            const float* Wb = (wsel == 0 ? Wq : Wa) + (size_t)(layer * 2 + t) * 16384;
            out = Wb[k * 128 + n];
        } else {
            int h = n >> 4, j = n & 15;
            const float* Wb = (wsel == 1 ? Wk : Wv) + (size_t)(layer * 2 + t) * 16384;
            const float* R = (wsel == 1 ? arel : mrel) + (size_t)((layer * 3 + e) * NH + h) * 256;
            float s = 0.f;
            #pragma unroll
            for (int d = 0; d < HD; ++d) s += Wb[k * 128 + h * 16 + d] * R[d * 16 + j];
            out = s;
        }
        Wl[(size_t)slot * 16384 + n * 128 + k] = f2bf(out);
    } else {
        int r = idx - WTOT;
        if (r < 10 * 128) {
            int slot = r >> 7, n = r & 127;
            int kind, wsel, e, t;
            slot_info(slot, kind, wsel, e, t);
            float out;
            if (kind == 0) {
                const float* bb = (wsel == 0 ? bq : ba) + (size_t)(layer * 2 + t) * 128;
                out = bb[n];
            } else {
                int h = n >> 4, j = n & 15;
                const float* bb = (wsel == 1 ? bk : bv) + (size_t)(layer * 2 + t) * 128;
                const float* R = (wsel == 1 ? arel : mrel) + (size_t)((layer * 3 + e) * NH + h) * 256;
                float s = 0.f;
                #pragma unroll
                for (int d = 0; d < HD; ++d) s += bb[h * 16 + d] * R[d * 16 + j];
                out = s;
            }
            bl[slot * 128 + n] = out;
        }
    }
}

// helper: slot -> output pointer mapping for qkv stores
__device__ __forceinline__ void qkv_slot_ptr(int side, int s,
    short* qA, short* kvA0, short* kvA2, short* qB, short* kvB1,
    short*& optr, int& old, int& ooff) {
    if (side) {
        if (s == 0)      { optr = qB;   old = 128; ooff = 0; }
        else if (s == 1) { optr = kvB1; old = 256; ooff = 0; }
        else             { optr = kvB1; old = 256; ooff = 128; }
    } else {
        if (s == 0)      { optr = qA;   old = 128; ooff = 0; }
        else if (s == 1) { optr = kvA0; old = 256; ooff = 0; }
        else if (s == 2) { optr = kvA0; old = 256; ooff = 128; }
        else if (s == 3) { optr = kvA2; old = 256; ooff = 0; }
        else             { optr = kvA2; old = 256; ooff = 128; }
    }
}

// ---- layer-0 QKV: f32 input, slot-looped, LDS-staged vector stores --------
__global__ __launch_bounds__(256) void gemm_qkv_all(
    const float* __restrict__ Aa, const float* __restrict__ Ab,
    const short* __restrict__ Wl, const float* __restrict__ bl,
    short* __restrict__ qA, short* __restrict__ kvA0, short* __restrict__ kvA2,
    short* __restrict__ qB, short* __restrict__ kvB1,
    int NA_, int NB_, int nbA) {
    __shared__ short Ws[128 * 136];
    __shared__ short As[64 * 136];
    float* Wsf = (float*)Ws;
    const int tid = threadIdx.x;
    const int bid = blockIdx.x;
    const int side = bid >= nbA;
    const float* A = side ? Ab : Aa;
    const int N = side ? NB_ : NA_;
    const int row0 = (side ? bid - nbA : bid) * 64;
    const short* Wbase = Wl + (side ? (size_t)5 * 16384 : 0);
    const float* bbase = bl + (side ? 5 * 128 : 0);
    const int S = side ? 3 : 5;

    #pragma unroll
    for (int it = 0; it < 4; ++it) {
        int chunk = tid + it * 256;
        int r = chunk >> 4, c8 = (chunk & 15) * 8;
        int gr = row0 + r;
        bf16x8 s = {};
        if (gr < N) {
            float4 v0 = *(const float4*)&A[(size_t)gr * F + c8];
            float4 v1 = *(const float4*)&A[(size_t)gr * F + c8 + 4];
            s[0] = f2bf(v0.x); s[1] = f2bf(v0.y); s[2] = f2bf(v0.z); s[3] = f2bf(v0.w);
            s[4] = f2bf(v1.x); s[5] = f2bf(v1.y); s[6] = f2bf(v1.z); s[7] = f2bf(v1.w);
        }
        *(bf16x8*)&As[r * 136 + c8] = s;
    }
    __syncthreads();

    const int wave = tid >> 6;
    const int lane = tid & 63;
    const int m16 = lane & 15;
    const int kg = lane >> 4;
    const int arow = wave * 16 + m16;

    bf16x8 af[4];
    #pragma unroll
    for (int kq = 0; kq < 4; ++kq)
        af[kq] = *(const bf16x8*)&As[arow * 136 + kq * 32 + kg * 8];

    for (int s = 0; s < S; ++s) {
        if (s) __syncthreads();
        const short* Wt = Wbase + (size_t)s * 16384;
        #pragma unroll
        for (int it = 0; it < 8; ++it) {
            int chunk = tid + it * 256;
            int r = chunk >> 4, c8 = (chunk & 15) * 8;
            *(int4*)&Ws[r * 136 + c8] = *(const int4*)&Wt[r * 128 + c8];
        }
        __syncthreads();

        f32x4 acc[8] = {};
        #pragma unroll
        for (int kq = 0; kq < 4; ++kq) {
            #pragma unroll
            for (int nt = 0; nt < 8; ++nt) {
                bf16x8 b = *(const bf16x8*)&Ws[(nt * 16 + m16) * 136 + kq * 32 + kg * 8];
                acc[nt] = __builtin_amdgcn_mfma_f32_16x16x32_bf16(af[kq], b, acc[nt], 0, 0, 0);
            }
        }
        __syncthreads();

        #pragma unroll
        for (int nt = 0; nt < 8; ++nt)
            #pragma unroll
            for (int r = 0; r < 4; ++r)
                Wsf[(wave * 16 + kg * 4 + r) * 132 + nt * 16 + m16] = acc[nt][r];
        __syncthreads();

        short* optr; int old, ooff;
        qkv_slot_ptr(side, s, qA, kvA0, kvA2, qB, kvB1, optr, old, ooff);
        const float* bias = bbase + s * 128;
        #pragma unroll
        for (int it = 0; it < 4; ++it) {
            int chunk = tid + it * 256;
            int r = chunk >> 4, c8 = (chunk & 15) * 8;
            int gr = row0 + r;
            if (gr >= N) continue;
            float4 b0 = *(const float4*)&bias[c8];
            float4 b1 = *(const float4*)&bias[c8 + 4];
            bf16x8 o;
            o[0] = f2bf(Wsf[r * 132 + c8 + 0] + b0.x);
            o[1] = f2bf(Wsf[r * 132 + c8 + 1] + b0.y);
            o[2] = f2bf(Wsf[r * 132 + c8 + 2] + b0.z);
            o[3] = f2bf(Wsf[r * 132 + c8 + 3] + b0.w);
            o[4] = f2bf(Wsf[r * 132 + c8 + 4] + b1.x);
            o[5] = f2bf(Wsf[r * 132 + c8 + 5] + b1.y);
            o[6] = f2bf(Wsf[r * 132 + c8 + 6] + b1.z);
            o[7] = f2bf(Wsf[r * 132 + c8 + 7] + b1.w);
            *(bf16x8*)&optr[(size_t)gr * old + ooff + c8] = o;
        }
    }
}

// ---- FUSED: layer-0 out-projection + layer-1 QKV --------------------------
// out0 = relu(sg*(gelu(agg)@Wa0+ba0) + (1-sg)*x) -> x1 (bf16, global + LDS),
// then 5/3-slot layer-1 QKV GEMM from the LDS-resident x1.
__global__ __launch_bounds__(256) void fused_out_qkv(
    const short* __restrict__ aggA, const short* __restrict__ aggB,
    const short* __restrict__ Wl0, const float* __restrict__ bl0,
    const float* __restrict__ xfA, const float* __restrict__ xfB,
    const float* __restrict__ skipp,
    const short* __restrict__ Wl1, const float* __restrict__ bl1,
    short* __restrict__ x1A, short* __restrict__ x1B,
    short* __restrict__ qA, short* __restrict__ kvA0, short* __restrict__ kvA2,
    short* __restrict__ qB, short* __restrict__ kvB1,
    int NA_, int NB_, int nbA) {
    __shared__ short Ws[128 * 136];
    __shared__ short As[64 * 136];
    float* Wsf = (float*)Ws;
    const int tid = threadIdx.x;
    const int bid = blockIdx.x;
    const int side = bid >= nbA;
    const short* A = side ? aggB : aggA;
    const int N = side ? NB_ : NA_;
    const int row0 = (side ? bid - nbA : bid) * 64;
    const short* Wt0 = Wl0 + (size_t)(side ? 9 : 8) * 16384;
    const float* bias0 = bl0 + (side ? 9 : 8) * 128;

    // stage Wa + gelu(agg)
    #pragma unroll
    for (int it = 0; it < 8; ++it) {
        int chunk = tid + it * 256;
        int r = chunk >> 4, c8 = (chunk & 15) * 8;
        *(int4*)&Ws[r * 136 + c8] = *(const int4*)&Wt0[r * 128 + c8];
    }
    #pragma unroll
    for (int it = 0; it < 4; ++it) {
        int chunk = tid + it * 256;
        int r = chunk >> 4, c8 = (chunk & 15) * 8;
        int gr = row0 + r;
        bf16x8 s = {};
        if (gr < N) {
            s = *(const bf16x8*)&A[(size_t)gr * F + c8];
            #pragma unroll
            for (int u = 0; u < 8; ++u) s[u] = f2bf(geluf(bf2f(s[u])));
        }
        *(bf16x8*)&As[r * 136 + c8] = s;
    }
    __syncthreads();

    const int wave = tid >> 6;
    const int lane = tid & 63;
    const int m16 = lane & 15;
    const int kg = lane >> 4;
    const int arow = wave * 16 + m16;

    {   // out-projection MFMA
        f32x4 acc[8] = {};
        #pragma unroll
        for (int k0 = 0; k0 < 128; k0 += 32) {
            bf16x8 a = *(const bf16x8*)&As[arow * 136 + k0 + kg * 8];
            #pragma unroll
            for (int nt = 0; nt < 8; ++nt) {
                bf16x8 b = *(const bf16x8*)&Ws[(nt * 16 + m16) * 136 + k0 + kg * 8];
                acc[nt] = __builtin_amdgcn_mfma_f32_16x16x32_bf16(a, b, acc[nt], 0, 0, 0);
            }
        }
        __syncthreads();
        #pragma unroll
        for (int nt = 0; nt < 8; ++nt)
            #pragma unroll
            for (int r = 0; r < 4; ++r)
                Wsf[(wave * 16 + kg * 4 + r) * 132 + nt * 16 + m16] = acc[nt][r];
        __syncthreads();
    }

    // epilogue: x1 = relu(skip-gate); store global bf16 AND write into As
    {
        float sg = 1.f / (1.f + expf(-skipp[side]));
        short* x1 = side ? x1B : x1A;
        const float* xf = side ? xfB : xfA;
        #pragma unroll
        for (int it = 0; it < 4; ++it) {
            int chunk = tid + it * 256;
            int r = chunk >> 4, c8 = (chunk & 15) * 8;
            int gr = row0 + r;
            if (gr >= N) continue;
            float4 b0 = *(const float4*)&bias0[c8];
            float4 b1 = *(const float4*)&bias0[c8 + 4];
            float4 x0v = *(const float4*)&xf[(size_t)gr * F + c8];
            float4 x1v = *(const float4*)&xf[(size_t)gr * F + c8 + 4];
            float v[8];
            #pragma unroll
            for (int u = 0; u < 8; ++u) v[u] = Wsf[r * 132 + c8 + u];
            v[0] += b0.x; v[1] += b0.y; v[2] += b0.z; v[3] += b0.w;
            v[4] += b1.x; v[5] += b1.y; v[6] += b1.z; v[7] += b1.w;
            float xr[8] = {x0v.x, x0v.y, x0v.z, x0v.w, x1v.x, x1v.y, x1v.z, x1v.w};
            bf16x8 o;
            #pragma unroll
            for (int u = 0; u < 8; ++u)
                o[u] = f2bf(fmaxf(sg * v[u] + (1.f - sg) * xr[u], 0.f));
            *(bf16x8*)&x1[(size_t)gr * F + c8] = o;
            *(bf16x8*)&As[r * 136 + c8] = o;
        }
    }
    __syncthreads();

    // layer-1 QKV from LDS-resident x1
    bf16x8 af[4];
    #pragma unroll
    for (int kq = 0; kq < 4; ++kq)
        af[kq] = *(const bf16x8*)&As[arow * 136 + kq * 32 + kg * 8];

    const short* Wbase = Wl1 + (side ? (size_t)5 * 16384 : 0);
    const float* bbase = bl1 + (side ? 5 * 128 : 0);
    const int S = side ? 3 : 5;

    for (int s = 0; s < S; ++s) {
        __syncthreads();
        const short* Wt = Wbase + (size_t)s * 16384;
        #pragma unroll
        for (int it = 0; it < 8; ++it) {
            int chunk = tid + it * 256;
            int r = chunk >> 4, c8 = (chunk & 15) * 8;
            *(int4*)&Ws[r * 136 + c8] = *(const int4*)&Wt[r * 128 + c8];
        }
        __syncthreads();

        f32x4 acc[8] = {};
        #pragma unroll
        for (int kq = 0; kq < 4; ++kq) {
            #pragma unroll
            for (int nt = 0; nt < 8; ++nt) {
                bf16x8 b = *(const bf16x8*)&Ws[(nt * 16 + m16) * 136 + kq * 32 + kg * 8];
                acc[nt] = __builtin_amdgcn_mfma_f32_16x16x32_bf16(af[kq], b, acc[nt], 0, 0, 0);
            }
        }
        __syncthreads();

        #pragma unroll
        for (int nt = 0; nt < 8; ++nt)
            #pragma unroll
            for (int r = 0; r < 4; ++r)
                Wsf[(wave * 16 + kg * 4 + r) * 132 + nt * 16 + m16] = acc[nt][r];
        __syncthreads();

        short* optr; int old, ooff;
        qkv_slot_ptr(side, s, qA, kvA0, kvA2, qB, kvB1, optr, old, ooff);
        const float* bias = bbase + s * 128;
        #pragma unroll
        for (int it = 0; it < 4; ++it) {
            int chunk = tid + it * 256;
            int r = chunk >> 4, c8 = (chunk & 15) * 8;
            int gr = row0 + r;
            if (gr >= N) continue;
            float4 b0 = *(const float4*)&bias[c8];
            float4 b1 = *(const float4*)&bias[c8 + 4];
            bf16x8 o;
            o[0] = f2bf(Wsf[r * 132 + c8 + 0] + b0.x);
            o[1] = f2bf(Wsf[r * 132 + c8 + 1] + b0.y);
            o[2] = f2bf(Wsf[r * 132 + c8 + 2] + b0.z);
            o[3] = f2bf(Wsf[r * 132 + c8 + 3] + b0.w);
            o[4] = f2bf(Wsf[r * 132 + c8 + 4] + b1.x);
            o[5] = f2bf(Wsf[r * 132 + c8 + 5] + b1.y);
            o[6] = f2bf(Wsf[r * 132 + c8 + 6] + b1.z);
            o[7] = f2bf(Wsf[r * 132 + c8 + 7] + b1.w);
            *(bf16x8*)&optr[(size_t)gr * old + ooff + c8] = o;
        }
    }
}

// ---- final out-projection (layer 1): bf16 residual, f32 output ------------
__global__ __launch_bounds__(256) void gemm_out_final(
    const short* __restrict__ aggA, const short* __restrict__ aggB,
    const short* __restrict__ Wl, const float* __restrict__ bl,
    const short* __restrict__ xbA, const short* __restrict__ xbB,
    const float* __restrict__ skipp,
    float* __restrict__ CfA, float* __restrict__ CfB,
    int NA_, int NB_, int nbA) {
    __shared__ short Ws[128 * 136];
    __shared__ short As[64 * 136];
    float* Wsf = (float*)Ws;
    const int tid = threadIdx.x;
    const int bid = blockIdx.x;
    const int side = bid >= nbA;
    const short* A = side ? aggB : aggA;
    const int N = side ? NB_ : NA_;
    const int row0 = (side ? bid - nbA : bid) * 64;
    const short* Wt = Wl + (size_t)(side ? 9 : 8) * 16384;
    const float* bias = bl + (side ? 9 : 8) * 128;

    #pragma unroll
    for (int it = 0; it < 8; ++it) {
        int chunk = tid + it * 256;
        int r = chunk >> 4, c8 = (chunk & 15) * 8;
        *(int4*)&Ws[r * 136 + c8] = *(const int4*)&Wt[r * 128 + c8];
    }
    #pragma unroll
    for (int it = 0; it < 4; ++it) {
        int chunk = tid + it * 256;
        int r = chunk >> 4, c8 = (chunk & 15) * 8;
        int gr = row0 + r;
        bf16x8 s = {};
        if (gr < N) {
            s = *(const bf16x8*)&A[(size_t)gr * F + c8];
            #pragma unroll
            for (int u = 0; u < 8; ++u) s[u] = f2bf(geluf(bf2f(s[u])));
        }
        *(bf16x8*)&As[r * 136 + c8] = s;
    }
    __syncthreads();

    const int wave = tid >> 6;
    const int lane = tid & 63;
    const int m16 = lane & 15;
    const int kg = lane >> 4;
    const int arow = wave * 16 + m16;

    f32x4 acc[8] = {};
    #pragma unroll
    for (int k0 = 0; k0 < 128; k0 += 32) {
        bf16x8 a = *(const bf16x8*)&As[arow * 136 + k0 + kg * 8];
        #pragma unroll
        for (int nt = 0; nt < 8; ++nt) {
            bf16x8 b = *(const bf16x8*)&Ws[(nt * 16 + m16) * 136 + k0 + kg * 8];
            acc[nt] = __builtin_amdgcn_mfma_f32_16x16x32_bf16(a, b, acc[nt], 0, 0, 0);
        }
    }
    __syncthreads();

    #pragma unroll
    for (int nt = 0; nt < 8; ++nt)
        #pragma unroll
        for (int r = 0; r < 4; ++r)
            Wsf[(wave * 16 + kg * 4 + r) * 132 + nt * 16 + m16] = acc[nt][r];
    __syncthreads();

    float sg = 1.f / (1.f + expf(-skipp[side]));
    #pragma unroll
    for (int it = 0; it < 4; ++it) {
        int chunk = tid + it * 256;
        int r = chunk >> 4, c8 = (chunk & 15) * 8;
        int gr = row0 + r;
        if (gr >= N) continue;
        float4 b0 = *(const float4*)&bias[c8];
        float4 b1 = *(const float4*)&bias[c8 + 4];
        float v[8];
        #pragma unroll
        for (int u = 0; u < 8; ++u) v[u] = Wsf[r * 132 + c8 + u];
        v[0] += b0.x; v[1] += b0.y; v[2] += b0.z; v[3] += b0.w;
        v[4] += b1.x; v[5] += b1.y; v[6] += b1.z; v[7] += b1.w;
        const short* xb = side ? xbB : xbA;
        bf16x8 xrv = *(const bf16x8*)&xb[(size_t)gr * F + c8];
        float* Cf = side ? CfB : CfA;
        float o[8];
        #pragma unroll
        for (int u = 0; u < 8; ++u)
            o[u] = sg * v[u] + (1.f - sg) * bf2f(xrv[u]);
        *(float4*)&Cf[(size_t)gr * F + c8]     = make_float4(o[0], o[1], o[2], o[3]);
        *(float4*)&Cf[(size_t)gr * F + c8 + 4] = make_float4(o[4], o[5], o[6], o[7]);
    }
}

// ---------------- combined CSR build ----------------------------------------

__global__ void hist_all(const int* __restrict__ ei0, const int* __restrict__ ei1,
                         const int* __restrict__ ei2, int E0, int E1, int E2,
                         int NB_, int NA_, int* __restrict__ cnt) {
    int i = blockIdx.x * 256 + threadIdx.x;
    if (i >= E0 + E1 + E2) return;
    const int* ei; int li, Ee, base;
    if (i < E0)           { li = i;           ei = ei0; Ee = E0; base = 0; }
    else if (i < E0 + E1) { li = i - E0;      ei = ei1; Ee = E1; base = NB_; }
    else                  { li = i - E0 - E1; ei = ei2; Ee = E2; base = NB_ + NA_; }
    atomicAdd(&cnt[base + ei[Ee + li]], 1);
}

__global__ void scan1(const int* __restrict__ cnt, int n, int* __restrict__ off,
                      int* __restrict__ bsum) {
    __shared__ int lds[256];
    int tid = threadIdx.x, i = blockIdx.x * 256 + tid;
    int v = (i < n) ? cnt[i] : 0;
    lds[tid] = v;
    __syncthreads();
    #pragma unroll
    for (int s = 1; s < 256; s <<= 1) {
        int t = (tid >= s) ? lds[tid - s] : 0;
        __syncthreads();
        lds[tid] += t;
        __syncthreads();
    }
    if (i < n) off[i] = lds[tid] - v;
    if (tid == 255) bsum[blockIdx.x] = lds[255];
}

__global__ __launch_bounds__(1024) void scan2(int* __restrict__ bsum, int nb,
                                              int* __restrict__ off_n) {
    __shared__ int lds[1024];
    int tid = threadIdx.x;
    int v = (tid < nb) ? bsum[tid] : 0;
    lds[tid] = v;
    __syncthreads();
    #pragma unroll
    for (int s = 1; s < 1024; s <<= 1) {
        int t = (tid >= s) ? lds[tid - s] : 0;
        __syncthreads();
        lds[tid] += t;
        __syncthreads();
    }
    if (tid < nb) bsum[tid] = lds[tid] - v;
    if (tid == 1023) *off_n = lds[1023];
}

__global__ void scan3(int* __restrict__ off, int* __restrict__ woff,
                      const int* __restrict__ bsum, int n) {
    int i = blockIdx.x * 256 + threadIdx.x;
    if (i < n) {
        int v = off[i] + bsum[blockIdx.x];
        off[i] = v;
        woff[i] = v;
    }
}

// stores PRE-SCALED src offsets (src * 128 = uint index of the kv row)
__global__ void scatter_all(const int* __restrict__ ei0, const int* __restrict__ ei1,
                            const int* __restrict__ ei2, int E0, int E1, int E2,
                            int NB_, int NA_, int* __restrict__ woff,
                            int* __restrict__ csr_src) {
    int i = blockIdx.x * 256 + threadIdx.x;
    if (i >= E0 + E1 + E2) return;
    const int* ei; int li, Ee, base;
    if (i < E0)           { li = i;           ei = ei0; Ee = E0; base = 0; }
    else if (i < E0 + E1) { li = i - E0;      ei = ei1; Ee = E1; base = NB_; }
    else                  { li = i - E0 - E1; ei = ei2; Ee = E2; base = NB_ + NA_; }
    int p = atomicAdd(&woff[base + ei[Ee + li]], 1);
    csr_src[p] = ei[li] * 128;
}

// ---- fused segment attention ----------------------------------------------
#define CH 8

// single-set core (type-b dsts)
__device__ __forceinline__ void seg_attn_one(
    const unsigned int* __restrict__ q32,
    const unsigned int* __restrict__ kv1, const int* __restrict__ off1,
    const int* __restrict__ csr_src, const float* __restrict__ prel1,
    unsigned int* __restrict__ agg32, int Nd, int blk) {
    int dst = blk * 4 + (threadIdx.x >> 6);
    if (dst >= Nd) return;
    int l = threadIdx.x & 63;
    int h = l >> 3;
    unsigned int qu = q32[(size_t)dst * 64 + l];
    float qlo = bflo(qu), qhi = bfhi(qu);
    float pr = prel1[h] * 0.25f;
    int c0 = off1[dst], e0 = off1[dst + 1];
    float m = -INFINITY, den = 0.f, alo = 0.f, ahi = 0.f;
    while (c0 < e0) {
        int n = e0 - c0; if (n > CH) n = CH;
        int sj[CH];
        unsigned int ku[CH], vu[CH];
        #pragma unroll
        for (int c = 0; c < CH; ++c) if (c < n) sj[c] = csr_src[c0 + c];
        #pragma unroll
        for (int c = 0; c < CH; ++c) if (c < n) {
            ku[c] = kv1[sj[c] + l];
            vu[c] = kv1[sj[c] + 64 + l];
        }
        float al[CH];
        float cmax = -INFINITY;
        #pragma unroll
        for (int c = 0; c < CH; ++c) if (c < n) {
            float p = bflo(ku[c]) * qlo + bfhi(ku[c]) * qhi;
            p += __shfl_xor(p, 4, 8);
            p += __shfl_xor(p, 2, 8);
            p += __shfl_xor(p, 1, 8);
            al[c] = p * pr;
            cmax = fmaxf(cmax, al[c]);
        }
        float nm = fmaxf(m, cmax);
        float corr = __expf(m - nm);
        den *= corr; alo *= corr; ahi *= corr;
        #pragma unroll
        for (int c = 0; c < CH; ++c) if (c < n) {
            float ex = __expf(al[c] - nm);
            den += ex;
            alo = fmaf(ex, bflo(vu[c]), alo);
            ahi = fmaf(ex, bfhi(vu[c]), ahi);
        }
        m = nm;
        c0 += n;
    }
    float inv = 1.f / (den + 1e-16f);
    unsigned int plo = (unsigned int)(unsigned short)f2bf(alo * inv);
    unsigned int phi = (unsigned int)(unsigned short)f2bf(ahi * inv);
    agg32[(size_t)dst * 64 + l] = plo | (phi << 16);
}

// dual-set core (type-a dsts): both sets' chunk loads issued before compute
__device__ __forceinline__ void seg_attn_dual(
    const unsigned int* __restrict__ q32,
    const unsigned int* __restrict__ kv1, const int* __restrict__ off1,
    const unsigned int* __restrict__ kv2, const int* __restrict__ off2,
    const int* __restrict__ csr_src,
    const float* __restrict__ prel1, const float* __restrict__ prel2,
    unsigned int* __restrict__ agg32, int Nd, int blk) {
    int dst = blk * 4 + (threadIdx.x >> 6);
    if (dst >= Nd) return;
    int l = threadIdx.x & 63;
    int h = l >> 3;
    unsigned int qu = q32[(size_t)dst * 64 + l];
    float qlo = bflo(qu), qhi = bfhi(qu);
    float pr0 = prel1[h] * 0.25f;
    float pr1 = prel2[h] * 0.25f;
    int c0 = off1[dst], e0 = off1[dst + 1];
    int c1 = off2[dst], e1 = off2[dst + 1];
    float m0 = -INFINITY, d0 = 0.f, lo0 = 0.f, hi0 = 0.f;
    float m1 = -INFINITY, d1 = 0.f, lo1 = 0.f, hi1 = 0.f;
    while (c0 < e0 || c1 < e1) {
        int n0 = e0 - c0; if (n0 > CH) n0 = CH; if (n0 < 0) n0 = 0;
        int n1 = e1 - c1; if (n1 > CH) n1 = CH; if (n1 < 0) n1 = 0;
        unsigned int ku0[CH], vu0[CH], ku1[CH], vu1[CH];
        {
            int sj[CH];
            #pragma unroll
            for (int c = 0; c < CH; ++c) if (c < n0) sj[c] = csr_src[c0 + c];
            #pragma unroll
            for (int c = 0; c < CH; ++c) if (c < n0) {
                ku0[c] = kv1[sj[c] + l];
                vu0[c] = kv1[sj[c] + 64 + l];
            }
        }
        {
            int sj[CH];
            #pragma unroll
            for (int c = 0; c < CH; ++c) if (c < n1) sj[c] = csr_src[c1 + c];
            #pragma unroll
            for (int c = 0; c < CH; ++c) if (c < n1) {
                ku1[c] = kv2[sj[c] + l];
                vu1[c] = kv2[sj[c] + 64 + l];
            }
        }
        if (n0 > 0) {    // wave-uniform branch
            float al[CH];
            float cmax = -INFINITY;
            #pragma unroll
            for (int c = 0; c < CH; ++c) if (c < n0) {
                float p = bflo(ku0[c]) * qlo + bfhi(ku0[c]) * qhi;
                p += __shfl_xor(p, 4, 8);
                p += __shfl_xor(p, 2, 8);
                p += __shfl_xor(p, 1, 8);
                al[c] = p * pr0;
                cmax = fmaxf(cmax, al[c]);
            }
            float nm = fmaxf(m0, cmax);
            float corr = __expf(m0 - nm);
            d0 *= corr; lo0 *= corr; hi0 *= corr;
            #pragma unroll
            for (int c = 0; c < CH; ++c) if (c < n0) {
                float ex = __expf(al[c] - nm);
                d0 += ex;
                lo0 = fmaf(ex, bflo(vu0[c]), lo0);
                hi0 = fmaf(ex, bfhi(vu0[c]), hi0);
            }
            m0 = nm;
        }
        if (n1 > 0) {
            float al[CH];
            float cmax = -INFINITY;
            #pragma unroll
            for (int c = 0; c < CH; ++c) if (c < n1) {
                float p = bflo(ku1[c]) * qlo + bfhi(ku1[c]) * qhi;
                p += __shfl_xor(p, 4, 8);
                p += __shfl_xor(p, 2, 8);
                p += __shfl_xor(p, 1, 8);
                al[c] = p * pr1;
                cmax = fmaxf(cmax, al[c]);
            }
            float nm = fmaxf(m1, cmax);
            float corr = __expf(m1 - nm);
            d1 *= corr; lo1 *= corr; hi1 *= corr;
            #pragma unroll
            for (int c = 0; c < CH; ++c) if (c < n1) {
                float ex = __expf(al[c] - nm);
                d1 += ex;
                lo1 = fmaf(ex, bflo(vu1[c]), lo1);
                hi1 = fmaf(ex, bfhi(vu1[c]), hi1);
            }
            m1 = nm;
        }
        c0 += n0; c1 += n1;
    }
    float inv0 = 1.f / (d0 + 1e-16f);
    float inv1 = 1.f / (d1 + 1e-16f);
    float rlo = lo0 * inv0 + lo1 * inv1;
    float rhi = hi0 * inv0 + hi1 * inv1;
    unsigned int plo = (unsigned int)(unsigned short)f2bf(rlo);
    unsigned int phi = (unsigned int)(unsigned short)f2bf(rhi);
    agg32[(size_t)dst * 64 + l] = plo | (phi << 16);
}

__global__ __launch_bounds__(256) void seg_attn_all(
    const short* __restrict__ qA, const short* __restrict__ kvA0,
    const short* __restrict__ kvA2, const short* __restrict__ qB,
    const short* __restrict__ kvB1,
    const int* __restrict__ off0, const int* __restrict__ off1,
    const int* __restrict__ off2, const int* __restrict__ csrS,
    const float* __restrict__ prelL,
    short* __restrict__ aggA, short* __restrict__ aggB,
    int NA_, int NB_, int nba) {
    if ((int)blockIdx.x < nba) {
        seg_attn_dual((const unsigned int*)qA,
                      (const unsigned int*)kvB1, off1,
                      (const unsigned int*)kvA2, off2, csrS,
                      prelL + 1 * NH, prelL + 2 * NH,
                      (unsigned int*)aggA, NA_, blockIdx.x);
    } else {
        seg_attn_one((const unsigned int*)qB,
                     (const unsigned int*)kvA0, off0, csrS,
                     prelL + 0 * NH,
                     (unsigned int*)aggB, NB_, blockIdx.x - nba);
    }
}

extern "C" void kernel_launch(void* const* d_in, const int* in_sizes, int n_in,
                              void* d_out, int out_size, void* d_ws, size_t ws_size,
                              hipStream_t stream) {
    const float* xa   = (const float*)d_in[0];
    const float* xb   = (const float*)d_in[1];
    const int* ei_ab  = (const int*)d_in[2];
    const int* ei_ba  = (const int*)d_in[3];
    const int* ei_aa  = (const int*)d_in[4];
    const float* Wk   = (const float*)d_in[5];
    const float* bk   = (const float*)d_in[6];
    const float* Wq   = (const float*)d_in[7];
    const float* bq   = (const float*)d_in[8];
    const float* Wv   = (const float*)d_in[9];
    const float* bv   = (const float*)d_in[10];
    const float* Wa   = (const float*)d_in[11];
    const float* ba   = (const float*)d_in[12];
    const float* skip = (const float*)d_in[13];
    const float* arel = (const float*)d_in[14];
    const float* mrel = (const float*)d_in[15];
    const float* prel = (const float*)d_in[16];

    const int NA = in_sizes[0] / F;
    const int NB = in_sizes[1] / F;
    const int E0 = in_sizes[2] / 2, E1 = in_sizes[3] / 2, E2 = in_sizes[4] / 2;
    const int ET = E0 + E1 + E2;
    const int NT = NB + NA + NA;   // combined dst space: e0 | e1 | e2

    float* ws = (float*)d_ws;
    size_t o = 0;
    float* bslots = ws + o; o += 2 * 10 * 128;
    // ints
    int* iws = (int*)(ws + o);
    size_t io = 0;
    int* cnt   = iws + io; io += NT;
    int* bsum  = iws + io; io += 1024;
    int* offc  = iws + io; io += NT + 1;
    int* woff  = iws + io; io += NT;
    int* csrS  = iws + io; io += ET;
    io = (io + 7) & ~(size_t)7;
    // shorts (bf16)
    short* sws = (short*)(iws + io);
    size_t so = 0;
    short* qA   = sws + so; so += (size_t)NA * 128;
    short* kvA0 = sws + so; so += (size_t)NA * 256;
    short* kvA2 = sws + so; so += (size_t)NA * 256;
    short* qB   = sws + so; so += (size_t)NB * 128;
    short* kvB1 = sws + so; so += (size_t)NB * 256;
    short* aggA = sws + so; so += (size_t)NA * 128;
    short* aggB = sws + so; so += (size_t)NB * 128;
    short* x1ab = sws + so; so += (size_t)NA * 128;
    short* x1bb = sws + so; so += (size_t)NB * 128;
    short* Wslots = sws + so; so += (size_t)2 * 10 * 16384;

    float* outA = (float*)d_out;
    float* outB = (float*)d_out + (size_t)NA * F;

    // ---- weights for both layers ----
    {
        dim3 g(cdiv(10 * 16384 + 10 * 128, 256), 2);
        prep_weights<<<g, 256, 0, stream>>>(Wk, bk, Wq, bq, Wv, bv, Wa, ba,
                                            arel, mrel, Wslots, bslots);
    }

    // ---- combined CSR ----
    hipMemsetAsync(cnt, 0, (size_t)NT * sizeof(int), stream);
    hist_all<<<cdiv(ET, 256), 256, 0, stream>>>(ei_ab, ei_ba, ei_aa, E0, E1, E2, NB, NA, cnt);
    {
        int nb = cdiv(NT, 256);
        scan1<<<nb, 256, 0, stream>>>(cnt, NT, offc, bsum);
        scan2<<<1, 1024, 0, stream>>>(bsum, nb, offc + NT);
        scan3<<<nb, 256, 0, stream>>>(offc, woff, bsum, NT);
    }
    scatter_all<<<cdiv(ET, 256), 256, 0, stream>>>(ei_ab, ei_ba, ei_aa, E0, E1, E2, NB, NA, woff, csrS);

    const int* off_e0 = offc;
    const int* off_e1 = offc + NB;
    const int* off_e2 = offc + NB + NA;

    const int nbA64 = cdiv(NA, 64), nbB64 = cdiv(NB, 64);
    const int nba4 = cdiv(NA, 4), nbb4 = cdiv(NB, 4);

    const short* Wl0 = Wslots;
    const short* Wl1 = Wslots + (size_t)10 * 16384;
    const float* bl0 = bslots;
    const float* bl1 = bslots + 10 * 128;

    // layer 0 QKV
    gemm_qkv_all<<<nbA64 + nbB64, 256, 0, stream>>>(
        xa, xb, Wl0, bl0, qA, kvA0, kvA2, qB, kvB1, NA, NB, nbA64);

    // layer 0 attention
    seg_attn_all<<<nba4 + nbb4, 256, 0, stream>>>(
        qA, kvA0, kvA2, qB, kvB1, off_e0, off_e1, off_e2, csrS,
        prel, aggA, aggB, NA, NB, nba4);

    // fused: layer-0 out-projection + layer-1 QKV
    fused_out_qkv<<<nbA64 + nbB64, 256, 0, stream>>>(
        aggA, aggB, Wl0, bl0, xa, xb, skip, Wl1, bl1,
        x1ab, x1bb, qA, kvA0, kvA2, qB, kvB1, NA, NB, nbA64);

    // layer 1 attention
    seg_attn_all<<<nba4 + nbb4, 256, 0, stream>>>(
        qA, kvA0, kvA2, qB, kvB1, off_e0, off_e1, off_e2, csrS,
        prel + 3 * NH, aggA, aggB, NA, NB, nba4);

    // final out-projection
    gemm_out_final<<<nbA64 + nbB64, 256, 0, stream>>>(
        aggA, aggB, Wl1, bl1, x1ab, x1bb, skip + 2, outA, outB, NA, NB, nbA64);
}

// Round 9
// 360.155 us; speedup vs baseline: 1.1699x; 1.1699x over previous
//
#include <hip/hip_runtime.h>
#include <hip/hip_bf16.h>
#include <math.h>

#define F 128
#define NH 8
#define HD 16

static inline int cdiv(int a, int b) { return (a + b - 1) / b; }

typedef __attribute__((ext_vector_type(8))) short bf16x8;
typedef __attribute__((ext_vector_type(4))) float f32x4;

__device__ __forceinline__ float geluf(float x) {
    return 0.5f * x * (1.f + erff(x * 0.70710678118654752440f));
}

__device__ __forceinline__ short f2bf(float f) {
    __hip_bfloat16 h = __float2bfloat16(f);
    return *reinterpret_cast<short*>(&h);
}

__device__ __forceinline__ float bflo(unsigned int u) { return __uint_as_float(u << 16); }
__device__ __forceinline__ float bfhi(unsigned int u) { return __uint_as_float(u & 0xffff0000u); }
__device__ __forceinline__ float bf2f(short s) {
    return __uint_as_float(((unsigned int)(unsigned short)s) << 16);
}

// ---- weight prep: per layer 10 slots of bf16 [n][k] + 10 f32 bias slots ----
// slot: 0 q(t0) | 1 k-fused e0 | 2 v-fused e0 | 3 k-fused e2 | 4 v-fused e2
//       5 q(t1) | 6 k-fused e1 | 7 v-fused e1 | 8 a(t0) | 9 a(t1)
__device__ __forceinline__ void slot_info(int slot, int& kind, int& wsel, int& e, int& t) {
    switch (slot) {
        case 0: kind = 0; wsel = 0; t = 0; e = 0; break;
        case 1: kind = 1; wsel = 1; t = 0; e = 0; break;
        case 2: kind = 1; wsel = 2; t = 0; e = 0; break;
        case 3: kind = 1; wsel = 1; t = 0; e = 2; break;
        case 4: kind = 1; wsel = 2; t = 0; e = 2; break;
        case 5: kind = 0; wsel = 0; t = 1; e = 0; break;
        case 6: kind = 1; wsel = 1; t = 1; e = 1; break;
        case 7: kind = 1; wsel = 2; t = 1; e = 1; break;
        case 8: kind = 0; wsel = 3; t = 0; e = 0; break;
        default: kind = 0; wsel = 3; t = 1; e = 0; break;
    }
}

__global__ void prep_weights(const float* __restrict__ Wk, const float* __restrict__ bk,
                             const float* __restrict__ Wq, const float* __restrict__ bq,
                             const float* __restrict__ Wv, const float* __restrict__ bv,
                             const float* __restrict__ Wa, const float* __restrict__ ba,
                             const float* __restrict__ arel, const float* __restrict__ mrel,
                             short* __restrict__ Wslots, float* __restrict__ bslots) {
    const int WTOT = 10 * 16384;
    const int layer = blockIdx.y;
    short* Wl = Wslots + (size_t)layer * WTOT;
    float* bl = bslots + (size_t)layer * 10 * 128;
    int idx = blockIdx.x * blockDim.x + threadIdx.x;
    if (idx < WTOT) {
        int slot = idx >> 14, rem = idx & 16383;
        int n = rem >> 7, k = rem & 127;
        int kind, wsel, e, t;
        slot_info(slot, kind, wsel, e, t);
        float out;
        if (kind == 0) {
            const float* Wb = (wsel == 0 ? Wq : Wa) + (size_t)(layer * 2 + t) * 16384;
            out = Wb[k * 128 + n];
        } else {
            int h = n >> 4, j = n & 15;
            const float* Wb = (wsel == 1 ? Wk : Wv) + (size_t)(layer * 2 + t) * 16384;
            const float* R = (wsel == 1 ? arel : mrel) + (size_t)((layer * 3 + e) * NH + h) * 256;
            float s = 0.f;
            #pragma unroll
            for (int d = 0; d < HD; ++d) s += Wb[k * 128 + h * 16 + d] * R[d * 16 + j];
            out = s;
        }
        Wl[(size_t)slot * 16384 + n * 128 + k] = f2bf(out);
    } else {
        int r = idx - WTOT;
        if (r < 10 * 128) {
            int slot = r >> 7, n = r & 127;
            int kind, wsel, e, t;
            slot_info(slot, kind, wsel, e, t);
            float out;
            if (kind == 0) {
                const float* bb = (wsel == 0 ? bq : ba) + (size_t)(layer * 2 + t) * 128;
                out = bb[n];
            } else {
                int h = n >> 4, j = n & 15;
                const float* bb = (wsel == 1 ? bk : bv) + (size_t)(layer * 2 + t) * 128;
                const float* R = (wsel == 1 ? arel : mrel) + (size_t)((layer * 3 + e) * NH + h) * 256;
                float s = 0.f;
                #pragma unroll
                for (int d = 0; d < HD; ++d) s += bb[h * 16 + d] * R[d * 16 + j];
                out = s;
            }
            bl[slot * 128 + n] = out;
        }
    }
}

// helper: slot -> output pointer for qkv stores (all [N][128] bf16)
__device__ __forceinline__ short* qkv_slot_ptr(int side, int s,
    short* qA, short* kA0, short* vA0, short* kA2, short* vA2,
    short* qB, short* kB1, short* vB1) {
    if (side) {
        if (s == 0) return qB;
        if (s == 1) return kB1;
        return vB1;
    }
    if (s == 0) return qA;
    if (s == 1) return kA0;
    if (s == 2) return vA0;
    if (s == 3) return kA2;
    return vA2;
}

// ---- layer-0 QKV: f32 input, slot-looped, LDS-staged vector stores --------
__global__ __launch_bounds__(256) void gemm_qkv_all(
    const float* __restrict__ Aa, const float* __restrict__ Ab,
    const short* __restrict__ Wl, const float* __restrict__ bl,
    short* __restrict__ qA, short* __restrict__ kA0, short* __restrict__ vA0,
    short* __restrict__ kA2, short* __restrict__ vA2,
    short* __restrict__ qB, short* __restrict__ kB1, short* __restrict__ vB1,
    int NA_, int NB_, int nbA) {
    __shared__ short Ws[128 * 136];
    __shared__ short As[64 * 136];
    float* Wsf = (float*)Ws;
    const int tid = threadIdx.x;
    const int bid = blockIdx.x;
    const int side = bid >= nbA;
    const float* A = side ? Ab : Aa;
    const int N = side ? NB_ : NA_;
    const int row0 = (side ? bid - nbA : bid) * 64;
    const short* Wbase = Wl + (side ? (size_t)5 * 16384 : 0);
    const float* bbase = bl + (side ? 5 * 128 : 0);
    const int S = side ? 3 : 5;

    #pragma unroll
    for (int it = 0; it < 4; ++it) {
        int chunk = tid + it * 256;
        int r = chunk >> 4, c8 = (chunk & 15) * 8;
        int gr = row0 + r;
        bf16x8 s = {};
        if (gr < N) {
            float4 v0 = *(const float4*)&A[(size_t)gr * F + c8];
            float4 v1 = *(const float4*)&A[(size_t)gr * F + c8 + 4];
            s[0] = f2bf(v0.x); s[1] = f2bf(v0.y); s[2] = f2bf(v0.z); s[3] = f2bf(v0.w);
            s[4] = f2bf(v1.x); s[5] = f2bf(v1.y); s[6] = f2bf(v1.z); s[7] = f2bf(v1.w);
        }
        *(bf16x8*)&As[r * 136 + c8] = s;
    }
    __syncthreads();

    const int wave = tid >> 6;
    const int lane = tid & 63;
    const int m16 = lane & 15;
    const int kg = lane >> 4;
    const int arow = wave * 16 + m16;

    bf16x8 af[4];
    #pragma unroll
    for (int kq = 0; kq < 4; ++kq)
        af[kq] = *(const bf16x8*)&As[arow * 136 + kq * 32 + kg * 8];

    for (int s = 0; s < S; ++s) {
        if (s) __syncthreads();
        const short* Wt = Wbase + (size_t)s * 16384;
        #pragma unroll
        for (int it = 0; it < 8; ++it) {
            int chunk = tid + it * 256;
            int r = chunk >> 4, c8 = (chunk & 15) * 8;
            *(int4*)&Ws[r * 136 + c8] = *(const int4*)&Wt[r * 128 + c8];
        }
        __syncthreads();

        f32x4 acc[8] = {};
        #pragma unroll
        for (int kq = 0; kq < 4; ++kq) {
            #pragma unroll
            for (int nt = 0; nt < 8; ++nt) {
                bf16x8 b = *(const bf16x8*)&Ws[(nt * 16 + m16) * 136 + kq * 32 + kg * 8];
                acc[nt] = __builtin_amdgcn_mfma_f32_16x16x32_bf16(af[kq], b, acc[nt], 0, 0, 0);
            }
        }
        __syncthreads();

        #pragma unroll
        for (int nt = 0; nt < 8; ++nt)
            #pragma unroll
            for (int r = 0; r < 4; ++r)
                Wsf[(wave * 16 + kg * 4 + r) * 132 + nt * 16 + m16] = acc[nt][r];
        __syncthreads();

        short* optr = qkv_slot_ptr(side, s, qA, kA0, vA0, kA2, vA2, qB, kB1, vB1);
        const float* bias = bbase + s * 128;
        #pragma unroll
        for (int it = 0; it < 4; ++it) {
            int chunk = tid + it * 256;
            int r = chunk >> 4, c8 = (chunk & 15) * 8;
            int gr = row0 + r;
            if (gr >= N) continue;
            float4 b0 = *(const float4*)&bias[c8];
            float4 b1 = *(const float4*)&bias[c8 + 4];
            bf16x8 o;
            o[0] = f2bf(Wsf[r * 132 + c8 + 0] + b0.x);
            o[1] = f2bf(Wsf[r * 132 + c8 + 1] + b0.y);
            o[2] = f2bf(Wsf[r * 132 + c8 + 2] + b0.z);
            o[3] = f2bf(Wsf[r * 132 + c8 + 3] + b0.w);
            o[4] = f2bf(Wsf[r * 132 + c8 + 4] + b1.x);
            o[5] = f2bf(Wsf[r * 132 + c8 + 5] + b1.y);
            o[6] = f2bf(Wsf[r * 132 + c8 + 6] + b1.z);
            o[7] = f2bf(Wsf[r * 132 + c8 + 7] + b1.w);
            *(bf16x8*)&optr[(size_t)gr * F + c8] = o;
        }
    }
}

// ---- FUSED: layer-0 out-projection + layer-1 QKV --------------------------
__global__ __launch_bounds__(256) void fused_out_qkv(
    const short* __restrict__ aggA, const short* __restrict__ aggB,
    const short* __restrict__ Wl0, const float* __restrict__ bl0,
    const float* __restrict__ xfA, const float* __restrict__ xfB,
    const float* __restrict__ skipp,
    const short* __restrict__ Wl1, const float* __restrict__ bl1,
    short* __restrict__ x1A, short* __restrict__ x1B,
    short* __restrict__ qA, short* __restrict__ kA0, short* __restrict__ vA0,
    short* __restrict__ kA2, short* __restrict__ vA2,
    short* __restrict__ qB, short* __restrict__ kB1, short* __restrict__ vB1,
    int NA_, int NB_, int nbA) {
    __shared__ short Ws[128 * 136];
    __shared__ short As[64 * 136];
    float* Wsf = (float*)Ws;
    const int tid = threadIdx.x;
    const int bid = blockIdx.x;
    const int side = bid >= nbA;
    const short* A = side ? aggB : aggA;
    const int N = side ? NB_ : NA_;
    const int row0 = (side ? bid - nbA : bid) * 64;
    const short* Wt0 = Wl0 + (size_t)(side ? 9 : 8) * 16384;
    const float* bias0 = bl0 + (side ? 9 : 8) * 128;

    #pragma unroll
    for (int it = 0; it < 8; ++it) {
        int chunk = tid + it * 256;
        int r = chunk >> 4, c8 = (chunk & 15) * 8;
        *(int4*)&Ws[r * 136 + c8] = *(const int4*)&Wt0[r * 128 + c8];
    }
    #pragma unroll
    for (int it = 0; it < 4; ++it) {
        int chunk = tid + it * 256;
        int r = chunk >> 4, c8 = (chunk & 15) * 8;
        int gr = row0 + r;
        bf16x8 s = {};
        if (gr < N) {
            s = *(const bf16x8*)&A[(size_t)gr * F + c8];
            #pragma unroll
            for (int u = 0; u < 8; ++u) s[u] = f2bf(geluf(bf2f(s[u])));
        }
        *(bf16x8*)&As[r * 136 + c8] = s;
    }
    __syncthreads();

    const int wave = tid >> 6;
    const int lane = tid & 63;
    const int m16 = lane & 15;
    const int kg = lane >> 6 == 0 ? (lane >> 4) : (lane >> 4);   // = lane>>4
    const int kgv = lane >> 4;
    const int arow = wave * 16 + m16;

    {   // out-projection MFMA
        f32x4 acc[8] = {};
        #pragma unroll
        for (int k0 = 0; k0 < 128; k0 += 32) {
            bf16x8 a = *(const bf16x8*)&As[arow * 136 + k0 + kgv * 8];
            #pragma unroll
            for (int nt = 0; nt < 8; ++nt) {
                bf16x8 b = *(const bf16x8*)&Ws[(nt * 16 + m16) * 136 + k0 + kgv * 8];
                acc[nt] = __builtin_amdgcn_mfma_f32_16x16x32_bf16(a, b, acc[nt], 0, 0, 0);
            }
        }
        __syncthreads();
        #pragma unroll
        for (int nt = 0; nt < 8; ++nt)
            #pragma unroll
            for (int r = 0; r < 4; ++r)
                Wsf[(wave * 16 + kgv * 4 + r) * 132 + nt * 16 + m16] = acc[nt][r];
        __syncthreads();
    }

    {   // epilogue: x1 = relu(skip-gate); store global bf16 AND write into As
        float sg = 1.f / (1.f + expf(-skipp[side]));
        short* x1 = side ? x1B : x1A;
        const float* xf = side ? xfB : xfA;
        #pragma unroll
        for (int it = 0; it < 4; ++it) {
            int chunk = tid + it * 256;
            int r = chunk >> 4, c8 = (chunk & 15) * 8;
            int gr = row0 + r;
            if (gr >= N) continue;
            float4 b0 = *(const float4*)&bias0[c8];
            float4 b1 = *(const float4*)&bias0[c8 + 4];
            float4 x0v = *(const float4*)&xf[(size_t)gr * F + c8];
            float4 x1v = *(const float4*)&xf[(size_t)gr * F + c8 + 4];
            float v[8];
            #pragma unroll
            for (int u = 0; u < 8; ++u) v[u] = Wsf[r * 132 + c8 + u];
            v[0] += b0.x; v[1] += b0.y; v[2] += b0.z; v[3] += b0.w;
            v[4] += b1.x; v[5] += b1.y; v[6] += b1.z; v[7] += b1.w;
            float xr[8] = {x0v.x, x0v.y, x0v.z, x0v.w, x1v.x, x1v.y, x1v.z, x1v.w};
            bf16x8 o;
            #pragma unroll
            for (int u = 0; u < 8; ++u)
                o[u] = f2bf(fmaxf(sg * v[u] + (1.f - sg) * xr[u], 0.f));
            *(bf16x8*)&x1[(size_t)gr * F + c8] = o;
            *(bf16x8*)&As[r * 136 + c8] = o;
        }
    }
    __syncthreads();

    // layer-1 QKV from LDS-resident x1
    bf16x8 af[4];
    #pragma unroll
    for (int kq = 0; kq < 4; ++kq)
        af[kq] = *(const bf16x8*)&As[arow * 136 + kq * 32 + kgv * 8];

    const short* Wbase = Wl1 + (side ? (size_t)5 * 16384 : 0);
    const float* bbase = bl1 + (side ? 5 * 128 : 0);
    const int S = side ? 3 : 5;

    for (int s = 0; s < S; ++s) {
        __syncthreads();
        const short* Wt = Wbase + (size_t)s * 16384;
        #pragma unroll
        for (int it = 0; it < 8; ++it) {
            int chunk = tid + it * 256;
            int r = chunk >> 4, c8 = (chunk & 15) * 8;
            *(int4*)&Ws[r * 136 + c8] = *(const int4*)&Wt[r * 128 + c8];
        }
        __syncthreads();

        f32x4 acc[8] = {};
        #pragma unroll
        for (int kq = 0; kq < 4; ++kq) {
            #pragma unroll
            for (int nt = 0; nt < 8; ++nt) {
                bf16x8 b = *(const bf16x8*)&Ws[(nt * 16 + m16) * 136 + kq * 32 + kgv * 8];
                acc[nt] = __builtin_amdgcn_mfma_f32_16x16x32_bf16(af[kq], b, acc[nt], 0, 0, 0);
            }
        }
        __syncthreads();

        #pragma unroll
        for (int nt = 0; nt < 8; ++nt)
            #pragma unroll
            for (int r = 0; r < 4; ++r)
                Wsf[(wave * 16 + kgv * 4 + r) * 132 + nt * 16 + m16] = acc[nt][r];
        __syncthreads();

        short* optr = qkv_slot_ptr(side, s, qA, kA0, vA0, kA2, vA2, qB, kB1, vB1);
        const float* bias = bbase + s * 128;
        #pragma unroll
        for (int it = 0; it < 4; ++it) {
            int chunk = tid + it * 256;
            int r = chunk >> 4, c8 = (chunk & 15) * 8;
            int gr = row0 + r;
            if (gr >= N) continue;
            float4 b0 = *(const float4*)&bias[c8];
            float4 b1 = *(const float4*)&bias[c8 + 4];
            bf16x8 o;
            o[0] = f2bf(Wsf[r * 132 + c8 + 0] + b0.x);
            o[1] = f2bf(Wsf[r * 132 + c8 + 1] + b0.y);
            o[2] = f2bf(Wsf[r * 132 + c8 + 2] + b0.z);
            o[3] = f2bf(Wsf[r * 132 + c8 + 3] + b0.w);
            o[4] = f2bf(Wsf[r * 132 + c8 + 4] + b1.x);
            o[5] = f2bf(Wsf[r * 132 + c8 + 5] + b1.y);
            o[6] = f2bf(Wsf[r * 132 + c8 + 6] + b1.z);
            o[7] = f2bf(Wsf[r * 132 + c8 + 7] + b1.w);
            *(bf16x8*)&optr[(size_t)gr * F + c8] = o;
        }
    }
}

// ---- final out-projection (layer 1): bf16 residual, f32 output ------------
__global__ __launch_bounds__(256) void gemm_out_final(
    const short* __restrict__ aggA, const short* __restrict__ aggB,
    const short* __restrict__ Wl, const float* __restrict__ bl,
    const short* __restrict__ xbA, const short* __restrict__ xbB,
    const float* __restrict__ skipp,
    float* __restrict__ CfA, float* __restrict__ CfB,
    int NA_, int NB_, int nbA) {
    __shared__ short Ws[128 * 136];
    __shared__ short As[64 * 136];
    float* Wsf = (float*)Ws;
    const int tid = threadIdx.x;
    const int bid = blockIdx.x;
    const int side = bid >= nbA;
    const short* A = side ? aggB : aggA;
    const int N = side ? NB_ : NA_;
    const int row0 = (side ? bid - nbA : bid) * 64;
    const short* Wt = Wl + (size_t)(side ? 9 : 8) * 16384;
    const float* bias = bl + (side ? 9 : 8) * 128;

    #pragma unroll
    for (int it = 0; it < 8; ++it) {
        int chunk = tid + it * 256;
        int r = chunk >> 4, c8 = (chunk & 15) * 8;
        *(int4*)&Ws[r * 136 + c8] = *(const int4*)&Wt[r * 128 + c8];
    }
    #pragma unroll
    for (int it = 0; it < 4; ++it) {
        int chunk = tid + it * 256;
        int r = chunk >> 4, c8 = (chunk & 15) * 8;
        int gr = row0 + r;
        bf16x8 s = {};
        if (gr < N) {
            s = *(const bf16x8*)&A[(size_t)gr * F + c8];
            #pragma unroll
            for (int u = 0; u < 8; ++u) s[u] = f2bf(geluf(bf2f(s[u])));
        }
        *(bf16x8*)&As[r * 136 + c8] = s;
    }
    __syncthreads();

    const int wave = tid >> 6;
    const int lane = tid & 63;
    const int m16 = lane & 15;
    const int kg = lane >> 4;
    const int arow = wave * 16 + m16;

    f32x4 acc[8] = {};
    #pragma unroll
    for (int k0 = 0; k0 < 128; k0 += 32) {
        bf16x8 a = *(const bf16x8*)&As[arow * 136 + k0 + kg * 8];
        #pragma unroll
        for (int nt = 0; nt < 8; ++nt) {
            bf16x8 b = *(const bf16x8*)&Ws[(nt * 16 + m16) * 136 + k0 + kg * 8];
            acc[nt] = __builtin_amdgcn_mfma_f32_16x16x32_bf16(a, b, acc[nt], 0, 0, 0);
        }
    }
    __syncthreads();

    #pragma unroll
    for (int nt = 0; nt < 8; ++nt)
        #pragma unroll
        for (int r = 0; r < 4; ++r)
            Wsf[(wave * 16 + kg * 4 + r) * 132 + nt * 16 + m16] = acc[nt][r];
    __syncthreads();

    float sg = 1.f / (1.f + expf(-skipp[side]));
    #pragma unroll
    for (int it = 0; it < 4; ++it) {
        int chunk = tid + it * 256;
        int r = chunk >> 4, c8 = (chunk & 15) * 8;
        int gr = row0 + r;
        if (gr >= N) continue;
        float4 b0 = *(const float4*)&bias[c8];
        float4 b1 = *(const float4*)&bias[c8 + 4];
        float v[8];
        #pragma unroll
        for (int u = 0; u < 8; ++u) v[u] = Wsf[r * 132 + c8 + u];
        v[0] += b0.x; v[1] += b0.y; v[2] += b0.z; v[3] += b0.w;
        v[4] += b1.x; v[5] += b1.y; v[6] += b1.z; v[7] += b1.w;
        const short* xb = side ? xbB : xbA;
        bf16x8 xrv = *(const bf16x8*)&xb[(size_t)gr * F + c8];
        float* Cf = side ? CfB : CfA;
        float o[8];
        #pragma unroll
        for (int u = 0; u < 8; ++u)
            o[u] = sg * v[u] + (1.f - sg) * bf2f(xrv[u]);
        *(float4*)&Cf[(size_t)gr * F + c8]     = make_float4(o[0], o[1], o[2], o[3]);
        *(float4*)&Cf[(size_t)gr * F + c8 + 4] = make_float4(o[4], o[5], o[6], o[7]);
    }
}

// ---------------- combined CSR build ----------------------------------------

__global__ void hist_all(const int* __restrict__ ei0, const int* __restrict__ ei1,
                         const int* __restrict__ ei2, int E0, int E1, int E2,
                         int NB_, int NA_, int* __restrict__ cnt) {
    int i = blockIdx.x * 256 + threadIdx.x;
    if (i >= E0 + E1 + E2) return;
    const int* ei; int li, Ee, base;
    if (i < E0)           { li = i;           ei = ei0; Ee = E0; base = 0; }
    else if (i < E0 + E1) { li = i - E0;      ei = ei1; Ee = E1; base = NB_; }
    else                  { li = i - E0 - E1; ei = ei2; Ee = E2; base = NB_ + NA_; }
    atomicAdd(&cnt[base + ei[Ee + li]], 1);
}

__global__ void scan1(const int* __restrict__ cnt, int n, int* __restrict__ off,
                      int* __restrict__ bsum) {
    __shared__ int lds[256];
    int tid = threadIdx.x, i = blockIdx.x * 256 + tid;
    int v = (i < n) ? cnt[i] : 0;
    lds[tid] = v;
    __syncthreads();
    #pragma unroll
    for (int s = 1; s < 256; s <<= 1) {
        int t = (tid >= s) ? lds[tid - s] : 0;
        __syncthreads();
        lds[tid] += t;
        __syncthreads();
    }
    if (i < n) off[i] = lds[tid] - v;
    if (tid == 255) bsum[blockIdx.x] = lds[255];
}

__global__ __launch_bounds__(1024) void scan2(int* __restrict__ bsum, int nb,
                                              int* __restrict__ off_n) {
    __shared__ int lds[1024];
    int tid = threadIdx.x;
    int v = (tid < nb) ? bsum[tid] : 0;
    lds[tid] = v;
    __syncthreads();
    #pragma unroll
    for (int s = 1; s < 1024; s <<= 1) {
        int t = (tid >= s) ? lds[tid - s] : 0;
        __syncthreads();
        lds[tid] += t;
        __syncthreads();
    }
    if (tid < nb) bsum[tid] = lds[tid] - v;
    if (tid == 1023) *off_n = lds[1023];
}

__global__ void scan3(int* __restrict__ off, int* __restrict__ woff,
                      const int* __restrict__ bsum, int n) {
    int i = blockIdx.x * 256 + threadIdx.x;
    if (i < n) {
        int v = off[i] + bsum[blockIdx.x];
        off[i] = v;
        woff[i] = v;
    }
}

// stores PRE-SCALED src offsets (src * 64 = uint row offset of [N][128] bf16)
__global__ void scatter_all(const int* __restrict__ ei0, const int* __restrict__ ei1,
                            const int* __restrict__ ei2, int E0, int E1, int E2,
                            int NB_, int NA_, int* __restrict__ woff,
                            int* __restrict__ csr_src) {
    int i = blockIdx.x * 256 + threadIdx.x;
    if (i >= E0 + E1 + E2) return;
    const int* ei; int li, Ee, base;
    if (i < E0)           { li = i;           ei = ei0; Ee = E0; base = 0; }
    else if (i < E0 + E1) { li = i - E0;      ei = ei1; Ee = E1; base = NB_; }
    else                  { li = i - E0 - E1; ei = ei2; Ee = E2; base = NB_ + NA_; }
    int p = atomicAdd(&woff[base + ei[Ee + li]], 1);
    csr_src[p] = ei[li] * 64;
}

// ---- fused segment attention, no-max softmax, lean waves ------------------
#define CH 8

// one edge-set: accumulates normalized result into rlo/rhi
__device__ __forceinline__ void seg_set(
    const unsigned int* __restrict__ kArr, const unsigned int* __restrict__ vArr,
    int c0, int e0, const int* __restrict__ csr_src, int l,
    float qlo, float qhi, float pr, float& rlo, float& rhi) {
    float den = 0.f, alo = 0.f, ahi = 0.f;
    while (c0 < e0) {
        int n = e0 - c0; if (n > CH) n = CH;
        int sj[CH];
        unsigned int ku[CH], vu[CH];
        #pragma unroll
        for (int c = 0; c < CH; ++c) if (c < n) sj[c] = csr_src[c0 + c];
        #pragma unroll
        for (int c = 0; c < CH; ++c) if (c < n) {
            ku[c] = kArr[sj[c] + l];
            vu[c] = vArr[sj[c] + l];
        }
        #pragma unroll
        for (int c = 0; c < CH; ++c) if (c < n) {
            float p = bflo(ku[c]) * qlo + bfhi(ku[c]) * qhi;
            p += __shfl_xor(p, 4, 8);
            p += __shfl_xor(p, 2, 8);
            p += __shfl_xor(p, 1, 8);
            float ex = __expf(fminf(p * pr, 80.f));   // clamp unreachable: identity
            den += ex;
            alo = fmaf(ex, bflo(vu[c]), alo);
            ahi = fmaf(ex, bfhi(vu[c]), ahi);
        }
        c0 += n;
    }
    float inv = 1.f / (den + 1e-16f);
    rlo = fmaf(alo, inv, rlo);
    rhi = fmaf(ahi, inv, rhi);
}

__global__ __launch_bounds__(256) void seg_attn_all(
    const short* __restrict__ qA, const short* __restrict__ kA0,
    const short* __restrict__ vA0, const short* __restrict__ kA2,
    const short* __restrict__ vA2, const short* __restrict__ qB,
    const short* __restrict__ kB1, const short* __restrict__ vB1,
    const int* __restrict__ off0, const int* __restrict__ off1,
    const int* __restrict__ off2, const int* __restrict__ csrS,
    const float* __restrict__ prelL,
    short* __restrict__ aggA, short* __restrict__ aggB,
    int NA_, int NB_, int nba) {
    int l = threadIdx.x & 63;
    int h = l >> 3;
    float rlo = 0.f, rhi = 0.f;
    if ((int)blockIdx.x < nba) {
        int dst = blockIdx.x * 4 + (threadIdx.x >> 6);
        if (dst >= NA_) return;
        unsigned int qu = ((const unsigned int*)qA)[(size_t)dst * 64 + l];
        float qlo = bflo(qu), qhi = bfhi(qu);
        seg_set((const unsigned int*)kB1, (const unsigned int*)vB1,
                off1[dst], off1[dst + 1], csrS, l, qlo, qhi,
                prelL[1 * NH + h] * 0.25f, rlo, rhi);
        seg_set((const unsigned int*)kA2, (const unsigned int*)vA2,
                off2[dst], off2[dst + 1], csrS, l, qlo, qhi,
                prelL[2 * NH + h] * 0.25f, rlo, rhi);
        unsigned int plo = (unsigned int)(unsigned short)f2bf(rlo);
        unsigned int phi = (unsigned int)(unsigned short)f2bf(rhi);
        ((unsigned int*)aggA)[(size_t)dst * 64 + l] = plo | (phi << 16);
    } else {
        int dst = (blockIdx.x - nba) * 4 + (threadIdx.x >> 6);
        if (dst >= NB_) return;
        unsigned int qu = ((const unsigned int*)qB)[(size_t)dst * 64 + l];
        float qlo = bflo(qu), qhi = bfhi(qu);
        seg_set((const unsigned int*)kA0, (const unsigned int*)vA0,
                off0[dst], off0[dst + 1], csrS, l, qlo, qhi,
                prelL[0 * NH + h] * 0.25f, rlo, rhi);
        unsigned int plo = (unsigned int)(unsigned short)f2bf(rlo);
        unsigned int phi = (unsigned int)(unsigned short)f2bf(rhi);
        ((unsigned int*)aggB)[(size_t)dst * 64 + l] = plo | (phi << 16);
    }
}

extern "C" void kernel_launch(void* const* d_in, const int* in_sizes, int n_in,
                              void* d_out, int out_size, void* d_ws, size_t ws_size,
                              hipStream_t stream) {
    const float* xa   = (const float*)d_in[0];
    const float* xb   = (const float*)d_in[1];
    const int* ei_ab  = (const int*)d_in[2];
    const int* ei_ba  = (const int*)d_in[3];
    const int* ei_aa  = (const int*)d_in[4];
    const float* Wk   = (const float*)d_in[5];
    const float* bk   = (const float*)d_in[6];
    const float* Wq   = (const float*)d_in[7];
    const float* bq   = (const float*)d_in[8];
    const float* Wv   = (const float*)d_in[9];
    const float* bv   = (const float*)d_in[10];
    const float* Wa   = (const float*)d_in[11];
    const float* ba   = (const float*)d_in[12];
    const float* skip = (const float*)d_in[13];
    const float* arel = (const float*)d_in[14];
    const float* mrel = (const float*)d_in[15];
    const float* prel = (const float*)d_in[16];

    const int NA = in_sizes[0] / F;
    const int NB = in_sizes[1] / F;
    const int E0 = in_sizes[2] / 2, E1 = in_sizes[3] / 2, E2 = in_sizes[4] / 2;
    const int ET = E0 + E1 + E2;
    const int NT = NB + NA + NA;   // combined dst space: e0 | e1 | e2

    float* ws = (float*)d_ws;
    size_t o = 0;
    float* bslots = ws + o; o += 2 * 10 * 128;
    // ints
    int* iws = (int*)(ws + o);
    size_t io = 0;
    int* cnt   = iws + io; io += NT;
    int* bsum  = iws + io; io += 1024;
    int* offc  = iws + io; io += NT + 1;
    int* woff  = iws + io; io += NT;
    int* csrS  = iws + io; io += ET;
    io = (io + 7) & ~(size_t)7;
    // shorts (bf16), all [N][128]
    short* sws = (short*)(iws + io);
    size_t so = 0;
    short* qA  = sws + so; so += (size_t)NA * 128;
    short* kA0 = sws + so; so += (size_t)NA * 128;
    short* vA0 = sws + so; so += (size_t)NA * 128;
    short* kA2 = sws + so; so += (size_t)NA * 128;
    short* vA2 = sws + so; so += (size_t)NA * 128;
    short* qB  = sws + so; so += (size_t)NB * 128;
    short* kB1 = sws + so; so += (size_t)NB * 128;
    short* vB1 = sws + so; so += (size_t)NB * 128;
    short* aggA = sws + so; so += (size_t)NA * 128;
    short* aggB = sws + so; so += (size_t)NB * 128;
    short* x1ab = sws + so; so += (size_t)NA * 128;
    short* x1bb = sws + so; so += (size_t)NB * 128;
    short* Wslots = sws + so; so += (size_t)2 * 10 * 16384;

    float* outA = (float*)d_out;
    float* outB = (float*)d_out + (size_t)NA * F;

    // ---- weights for both layers ----
    {
        dim3 g(cdiv(10 * 16384 + 10 * 128, 256), 2);
        prep_weights<<<g, 256, 0, stream>>>(Wk, bk, Wq, bq, Wv, bv, Wa, ba,
                                            arel, mrel, Wslots, bslots);
    }

    // ---- combined CSR ----
    hipMemsetAsync(cnt, 0, (size_t)NT * sizeof(int), stream);
    hist_all<<<cdiv(ET, 256), 256, 0, stream>>>(ei_ab, ei_ba, ei_aa, E0, E1, E2, NB, NA, cnt);
    {
        int nb = cdiv(NT, 256);
        scan1<<<nb, 256, 0, stream>>>(cnt, NT, offc, bsum);
        scan2<<<1, 1024, 0, stream>>>(bsum, nb, offc + NT);
        scan3<<<nb, 256, 0, stream>>>(offc, woff, bsum, NT);
    }
    scatter_all<<<cdiv(ET, 256), 256, 0, stream>>>(ei_ab, ei_ba, ei_aa, E0, E1, E2, NB, NA, woff, csrS);

    const int* off_e0 = offc;
    const int* off_e1 = offc + NB;
    const int* off_e2 = offc + NB + NA;

    const int nbA64 = cdiv(NA, 64), nbB64 = cdiv(NB, 64);
    const int nba4 = cdiv(NA, 4), nbb4 = cdiv(NB, 4);

    const short* Wl0 = Wslots;
    const short* Wl1 = Wslots + (size_t)10 * 16384;
    const float* bl0 = bslots;
    const float* bl1 = bslots + 10 * 128;

    // layer 0 QKV
    gemm_qkv_all<<<nbA64 + nbB64, 256, 0, stream>>>(
        xa, xb, Wl0, bl0, qA, kA0, vA0, kA2, vA2, qB, kB1, vB1, NA, NB, nbA64);

    // layer 0 attention
    seg_attn_all<<<nba4 + nbb4, 256, 0, stream>>>(
        qA, kA0, vA0, kA2, vA2, qB, kB1, vB1,
        off_e0, off_e1, off_e2, csrS, prel, aggA, aggB, NA, NB, nba4);

    // fused: layer-0 out-projection + layer-1 QKV
    fused_out_qkv<<<nbA64 + nbB64, 256, 0, stream>>>(
        aggA, aggB, Wl0, bl0, xa, xb, skip, Wl1, bl1,
        x1ab, x1bb, qA, kA0, vA0, kA2, vA2, qB, kB1, vB1, NA, NB, nbA64);

    // layer 1 attention
    seg_attn_all<<<nba4 + nbb4, 256, 0, stream>>>(
        qA, kA0, vA0, kA2, vA2, qB, kB1, vB1,
        off_e0, off_e1, off_e2, csrS, prel + 3 * NH, aggA, aggB, NA, NB, nba4);

    // final out-projection
    gemm_out_final<<<nbA64 + nbB64, 256, 0, stream>>>(
        aggA, aggB, Wl1, bl1, x1ab, x1bb, skip + 2, outA, outB, NA, NB, nbA64);
}

// Round 10
// 341.221 us; speedup vs baseline: 1.2348x; 1.0555x over previous
//
#include <hip/hip_runtime.h>
#include <hip/hip_bf16.h>
#include <math.h>

#define F 128
#define NH 8
#define HD 16

static inline int cdiv(int a, int b) { return (a + b - 1) / b; }

typedef __attribute__((ext_vector_type(8))) short bf16x8;
typedef __attribute__((ext_vector_type(4))) float f32x4;

__device__ __forceinline__ float geluf(float x) {
    return 0.5f * x * (1.f + erff(x * 0.70710678118654752440f));
}

__device__ __forceinline__ short f2bf(float f) {
    __hip_bfloat16 h = __float2bfloat16(f);
    return *reinterpret_cast<short*>(&h);
}

__device__ __forceinline__ float bflo(unsigned int u) { return __uint_as_float(u << 16); }
__device__ __forceinline__ float bfhi(unsigned int u) { return __uint_as_float(u & 0xffff0000u); }
__device__ __forceinline__ float bf2f(short s) {
    return __uint_as_float(((unsigned int)(unsigned short)s) << 16);
}
__device__ __forceinline__ unsigned int packbf(float a, float b) {
    return (unsigned int)(unsigned short)f2bf(a) | ((unsigned int)(unsigned short)f2bf(b) << 16);
}

// ---- weight prep: per layer 10 slots of bf16 [n][k] + 10 f32 bias slots ----
// slot: 0 q(t0) | 1 k-fused e0 | 2 v-fused e0 | 3 k-fused e2 | 4 v-fused e2
//       5 q(t1) | 6 k-fused e1 | 7 v-fused e1 | 8 a(t0) | 9 a(t1)
__device__ __forceinline__ void slot_info(int slot, int& kind, int& wsel, int& e, int& t) {
    switch (slot) {
        case 0: kind = 0; wsel = 0; t = 0; e = 0; break;
        case 1: kind = 1; wsel = 1; t = 0; e = 0; break;
        case 2: kind = 1; wsel = 2; t = 0; e = 0; break;
        case 3: kind = 1; wsel = 1; t = 0; e = 2; break;
        case 4: kind = 1; wsel = 2; t = 0; e = 2; break;
        case 5: kind = 0; wsel = 0; t = 1; e = 0; break;
        case 6: kind = 1; wsel = 1; t = 1; e = 1; break;
        case 7: kind = 1; wsel = 2; t = 1; e = 1; break;
        case 8: kind = 0; wsel = 3; t = 0; e = 0; break;
        default: kind = 0; wsel = 3; t = 1; e = 0; break;
    }
}

__global__ void prep_weights(const float* __restrict__ Wk, const float* __restrict__ bk,
                             const float* __restrict__ Wq, const float* __restrict__ bq,
                             const float* __restrict__ Wv, const float* __restrict__ bv,
                             const float* __restrict__ Wa, const float* __restrict__ ba,
                             const float* __restrict__ arel, const float* __restrict__ mrel,
                             short* __restrict__ Wslots, float* __restrict__ bslots) {
    const int WTOT = 10 * 16384;
    const int layer = blockIdx.y;
    short* Wl = Wslots + (size_t)layer * WTOT;
    float* bl = bslots + (size_t)layer * 10 * 128;
    int idx = blockIdx.x * blockDim.x + threadIdx.x;
    if (idx < WTOT) {
        int slot = idx >> 14, rem = idx & 16383;
        int n = rem >> 7, k = rem & 127;
        int kind, wsel, e, t;
        slot_info(slot, kind, wsel, e, t);
        float out;
        if (kind == 0) {
            const float* Wb = (wsel == 0 ? Wq : Wa) + (size_t)(layer * 2 + t) * 16384;
            out = Wb[k * 128 + n];
        } else {
            int h = n >> 4, j = n & 15;
            const float* Wb = (wsel == 1 ? Wk : Wv) + (size_t)(layer * 2 + t) * 16384;
            const float* R = (wsel == 1 ? arel : mrel) + (size_t)((layer * 3 + e) * NH + h) * 256;
            float s = 0.f;
            #pragma unroll
            for (int d = 0; d < HD; ++d) s += Wb[k * 128 + h * 16 + d] * R[d * 16 + j];
            out = s;
        }
        Wl[(size_t)slot * 16384 + n * 128 + k] = f2bf(out);
    } else {
        int r = idx - WTOT;
        if (r < 10 * 128) {
            int slot = r >> 7, n = r & 127;
            int kind, wsel, e, t;
            slot_info(slot, kind, wsel, e, t);
            float out;
            if (kind == 0) {
                const float* bb = (wsel == 0 ? bq : ba) + (size_t)(layer * 2 + t) * 128;
                out = bb[n];
            } else {
                int h = n >> 4, j = n & 15;
                const float* bb = (wsel == 1 ? bk : bv) + (size_t)(layer * 2 + t) * 128;
                const float* R = (wsel == 1 ? arel : mrel) + (size_t)((layer * 3 + e) * NH + h) * 256;
                float s = 0.f;
                #pragma unroll
                for (int d = 0; d < HD; ++d) s += bb[h * 16 + d] * R[d * 16 + j];
                out = s;
            }
            bl[slot * 128 + n] = out;
        }
    }
}

// helper: slot -> output pointer for qkv stores (all [N][128] bf16)
__device__ __forceinline__ short* qkv_slot_ptr(int side, int s,
    short* qA, short* kA0, short* vA0, short* kA2, short* vA2,
    short* qB, short* kB1, short* vB1) {
    if (side) {
        if (s == 0) return qB;
        if (s == 1) return kB1;
        return vB1;
    }
    if (s == 0) return qA;
    if (s == 1) return kA0;
    if (s == 2) return vA0;
    if (s == 3) return kA2;
    return vA2;
}

// ---- layer-0 QKV: f32 input, slot-looped, LDS-staged vector stores --------
__global__ __launch_bounds__(256) void gemm_qkv_all(
    const float* __restrict__ Aa, const float* __restrict__ Ab,
    const short* __restrict__ Wl, const float* __restrict__ bl,
    short* __restrict__ qA, short* __restrict__ kA0, short* __restrict__ vA0,
    short* __restrict__ kA2, short* __restrict__ vA2,
    short* __restrict__ qB, short* __restrict__ kB1, short* __restrict__ vB1,
    int NA_, int NB_, int nbA) {
    __shared__ short Ws[128 * 136];
    __shared__ short As[64 * 136];
    float* Wsf = (float*)Ws;
    const int tid = threadIdx.x;
    const int bid = blockIdx.x;
    const int side = bid >= nbA;
    const float* A = side ? Ab : Aa;
    const int N = side ? NB_ : NA_;
    const int row0 = (side ? bid - nbA : bid) * 64;
    const short* Wbase = Wl + (side ? (size_t)5 * 16384 : 0);
    const float* bbase = bl + (side ? 5 * 128 : 0);
    const int S = side ? 3 : 5;

    #pragma unroll
    for (int it = 0; it < 4; ++it) {
        int chunk = tid + it * 256;
        int r = chunk >> 4, c8 = (chunk & 15) * 8;
        int gr = row0 + r;
        bf16x8 s = {};
        if (gr < N) {
            float4 v0 = *(const float4*)&A[(size_t)gr * F + c8];
            float4 v1 = *(const float4*)&A[(size_t)gr * F + c8 + 4];
            s[0] = f2bf(v0.x); s[1] = f2bf(v0.y); s[2] = f2bf(v0.z); s[3] = f2bf(v0.w);
            s[4] = f2bf(v1.x); s[5] = f2bf(v1.y); s[6] = f2bf(v1.z); s[7] = f2bf(v1.w);
        }
        *(bf16x8*)&As[r * 136 + c8] = s;
    }
    __syncthreads();

    const int wave = tid >> 6;
    const int lane = tid & 63;
    const int m16 = lane & 15;
    const int kg = lane >> 4;
    const int arow = wave * 16 + m16;

    bf16x8 af[4];
    #pragma unroll
    for (int kq = 0; kq < 4; ++kq)
        af[kq] = *(const bf16x8*)&As[arow * 136 + kq * 32 + kg * 8];

    for (int s = 0; s < S; ++s) {
        if (s) __syncthreads();
        const short* Wt = Wbase + (size_t)s * 16384;
        #pragma unroll
        for (int it = 0; it < 8; ++it) {
            int chunk = tid + it * 256;
            int r = chunk >> 4, c8 = (chunk & 15) * 8;
            *(int4*)&Ws[r * 136 + c8] = *(const int4*)&Wt[r * 128 + c8];
        }
        __syncthreads();

        f32x4 acc[8] = {};
        #pragma unroll
        for (int kq = 0; kq < 4; ++kq) {
            #pragma unroll
            for (int nt = 0; nt < 8; ++nt) {
                bf16x8 b = *(const bf16x8*)&Ws[(nt * 16 + m16) * 136 + kq * 32 + kg * 8];
                acc[nt] = __builtin_amdgcn_mfma_f32_16x16x32_bf16(af[kq], b, acc[nt], 0, 0, 0);
            }
        }
        __syncthreads();

        #pragma unroll
        for (int nt = 0; nt < 8; ++nt)
            #pragma unroll
            for (int r = 0; r < 4; ++r)
                Wsf[(wave * 16 + kg * 4 + r) * 132 + nt * 16 + m16] = acc[nt][r];
        __syncthreads();

        short* optr = qkv_slot_ptr(side, s, qA, kA0, vA0, kA2, vA2, qB, kB1, vB1);
        const float* bias = bbase + s * 128;
        #pragma unroll
        for (int it = 0; it < 4; ++it) {
            int chunk = tid + it * 256;
            int r = chunk >> 4, c8 = (chunk & 15) * 8;
            int gr = row0 + r;
            if (gr >= N) continue;
            float4 b0 = *(const float4*)&bias[c8];
            float4 b1 = *(const float4*)&bias[c8 + 4];
            bf16x8 o;
            o[0] = f2bf(Wsf[r * 132 + c8 + 0] + b0.x);
            o[1] = f2bf(Wsf[r * 132 + c8 + 1] + b0.y);
            o[2] = f2bf(Wsf[r * 132 + c8 + 2] + b0.z);
            o[3] = f2bf(Wsf[r * 132 + c8 + 3] + b0.w);
            o[4] = f2bf(Wsf[r * 132 + c8 + 4] + b1.x);
            o[5] = f2bf(Wsf[r * 132 + c8 + 5] + b1.y);
            o[6] = f2bf(Wsf[r * 132 + c8 + 6] + b1.z);
            o[7] = f2bf(Wsf[r * 132 + c8 + 7] + b1.w);
            *(bf16x8*)&optr[(size_t)gr * F + c8] = o;
        }
    }
}

// ---- FUSED: layer-0 out-projection + layer-1 QKV --------------------------
__global__ __launch_bounds__(256) void fused_out_qkv(
    const short* __restrict__ aggA, const short* __restrict__ aggB,
    const short* __restrict__ Wl0, const float* __restrict__ bl0,
    const float* __restrict__ xfA, const float* __restrict__ xfB,
    const float* __restrict__ skipp,
    const short* __restrict__ Wl1, const float* __restrict__ bl1,
    short* __restrict__ x1A, short* __restrict__ x1B,
    short* __restrict__ qA, short* __restrict__ kA0, short* __restrict__ vA0,
    short* __restrict__ kA2, short* __restrict__ vA2,
    short* __restrict__ qB, short* __restrict__ kB1, short* __restrict__ vB1,
    int NA_, int NB_, int nbA) {
    __shared__ short Ws[128 * 136];
    __shared__ short As[64 * 136];
    float* Wsf = (float*)Ws;
    const int tid = threadIdx.x;
    const int bid = blockIdx.x;
    const int side = bid >= nbA;
    const short* A = side ? aggB : aggA;
    const int N = side ? NB_ : NA_;
    const int row0 = (side ? bid - nbA : bid) * 64;
    const short* Wt0 = Wl0 + (size_t)(side ? 9 : 8) * 16384;
    const float* bias0 = bl0 + (side ? 9 : 8) * 128;

    #pragma unroll
    for (int it = 0; it < 8; ++it) {
        int chunk = tid + it * 256;
        int r = chunk >> 4, c8 = (chunk & 15) * 8;
        *(int4*)&Ws[r * 136 + c8] = *(const int4*)&Wt0[r * 128 + c8];
    }
    #pragma unroll
    for (int it = 0; it < 4; ++it) {
        int chunk = tid + it * 256;
        int r = chunk >> 4, c8 = (chunk & 15) * 8;
        int gr = row0 + r;
        bf16x8 s = {};
        if (gr < N) {
            s = *(const bf16x8*)&A[(size_t)gr * F + c8];
            #pragma unroll
            for (int u = 0; u < 8; ++u) s[u] = f2bf(geluf(bf2f(s[u])));
        }
        *(bf16x8*)&As[r * 136 + c8] = s;
    }
    __syncthreads();

    const int wave = tid >> 6;
    const int lane = tid & 63;
    const int m16 = lane & 15;
    const int kgv = lane >> 4;
    const int arow = wave * 16 + m16;

    {   // out-projection MFMA
        f32x4 acc[8] = {};
        #pragma unroll
        for (int k0 = 0; k0 < 128; k0 += 32) {
            bf16x8 a = *(const bf16x8*)&As[arow * 136 + k0 + kgv * 8];
            #pragma unroll
            for (int nt = 0; nt < 8; ++nt) {
                bf16x8 b = *(const bf16x8*)&Ws[(nt * 16 + m16) * 136 + k0 + kgv * 8];
                acc[nt] = __builtin_amdgcn_mfma_f32_16x16x32_bf16(a, b, acc[nt], 0, 0, 0);
            }
        }
        __syncthreads();
        #pragma unroll
        for (int nt = 0; nt < 8; ++nt)
            #pragma unroll
            for (int r = 0; r < 4; ++r)
                Wsf[(wave * 16 + kgv * 4 + r) * 132 + nt * 16 + m16] = acc[nt][r];
        __syncthreads();
    }

    {   // epilogue: x1 = relu(skip-gate); store global bf16 AND write into As
        float sg = 1.f / (1.f + expf(-skipp[side]));
        short* x1 = side ? x1B : x1A;
        const float* xf = side ? xfB : xfA;
        #pragma unroll
        for (int it = 0; it < 4; ++it) {
            int chunk = tid + it * 256;
            int r = chunk >> 4, c8 = (chunk & 15) * 8;
            int gr = row0 + r;
            if (gr >= N) continue;
            float4 b0 = *(const float4*)&bias0[c8];
            float4 b1 = *(const float4*)&bias0[c8 + 4];
            float4 x0v = *(const float4*)&xf[(size_t)gr * F + c8];
            float4 x1v = *(const float4*)&xf[(size_t)gr * F + c8 + 4];
            float v[8];
            #pragma unroll
            for (int u = 0; u < 8; ++u) v[u] = Wsf[r * 132 + c8 + u];
            v[0] += b0.x; v[1] += b0.y; v[2] += b0.z; v[3] += b0.w;
            v[4] += b1.x; v[5] += b1.y; v[6] += b1.z; v[7] += b1.w;
            float xr[8] = {x0v.x, x0v.y, x0v.z, x0v.w, x1v.x, x1v.y, x1v.z, x1v.w};
            bf16x8 o;
            #pragma unroll
            for (int u = 0; u < 8; ++u)
                o[u] = f2bf(fmaxf(sg * v[u] + (1.f - sg) * xr[u], 0.f));
            *(bf16x8*)&x1[(size_t)gr * F + c8] = o;
            *(bf16x8*)&As[r * 136 + c8] = o;
        }
    }
    __syncthreads();

    // layer-1 QKV from LDS-resident x1
    bf16x8 af[4];
    #pragma unroll
    for (int kq = 0; kq < 4; ++kq)
        af[kq] = *(const bf16x8*)&As[arow * 136 + kq * 32 + kgv * 8];

    const short* Wbase = Wl1 + (side ? (size_t)5 * 16384 : 0);
    const float* bbase = bl1 + (side ? 5 * 128 : 0);
    const int S = side ? 3 : 5;

    for (int s = 0; s < S; ++s) {
        __syncthreads();
        const short* Wt = Wbase + (size_t)s * 16384;
        #pragma unroll
        for (int it = 0; it < 8; ++it) {
            int chunk = tid + it * 256;
            int r = chunk >> 4, c8 = (chunk & 15) * 8;
            *(int4*)&Ws[r * 136 + c8] = *(const int4*)&Wt[r * 128 + c8];
        }
        __syncthreads();

        f32x4 acc[8] = {};
        #pragma unroll
        for (int kq = 0; kq < 4; ++kq) {
            #pragma unroll
            for (int nt = 0; nt < 8; ++nt) {
                bf16x8 b = *(const bf16x8*)&Ws[(nt * 16 + m16) * 136 + kq * 32 + kgv * 8];
                acc[nt] = __builtin_amdgcn_mfma_f32_16x16x32_bf16(af[kq], b, acc[nt], 0, 0, 0);
            }
        }
        __syncthreads();

        #pragma unroll
        for (int nt = 0; nt < 8; ++nt)
            #pragma unroll
            for (int r = 0; r < 4; ++r)
                Wsf[(wave * 16 + kgv * 4 + r) * 132 + nt * 16 + m16] = acc[nt][r];
        __syncthreads();

        short* optr = qkv_slot_ptr(side, s, qA, kA0, vA0, kA2, vA2, qB, kB1, vB1);
        const float* bias = bbase + s * 128;
        #pragma unroll
        for (int it = 0; it < 4; ++it) {
            int chunk = tid + it * 256;
            int r = chunk >> 4, c8 = (chunk & 15) * 8;
            int gr = row0 + r;
            if (gr >= N) continue;
            float4 b0 = *(const float4*)&bias[c8];
            float4 b1 = *(const float4*)&bias[c8 + 4];
            bf16x8 o;
            o[0] = f2bf(Wsf[r * 132 + c8 + 0] + b0.x);
            o[1] = f2bf(Wsf[r * 132 + c8 + 1] + b0.y);
            o[2] = f2bf(Wsf[r * 132 + c8 + 2] + b0.z);
            o[3] = f2bf(Wsf[r * 132 + c8 + 3] + b0.w);
            o[4] = f2bf(Wsf[r * 132 + c8 + 4] + b1.x);
            o[5] = f2bf(Wsf[r * 132 + c8 + 5] + b1.y);
            o[6] = f2bf(Wsf[r * 132 + c8 + 6] + b1.z);
            o[7] = f2bf(Wsf[r * 132 + c8 + 7] + b1.w);
            *(bf16x8*)&optr[(size_t)gr * F + c8] = o;
        }
    }
}

// ---- final out-projection (layer 1): bf16 residual, f32 output ------------
__global__ __launch_bounds__(256) void gemm_out_final(
    const short* __restrict__ aggA, const short* __restrict__ aggB,
    const short* __restrict__ Wl, const float* __restrict__ bl,
    const short* __restrict__ xbA, const short* __restrict__ xbB,
    const float* __restrict__ skipp,
    float* __restrict__ CfA, float* __restrict__ CfB,
    int NA_, int NB_, int nbA) {
    __shared__ short Ws[128 * 136];
    __shared__ short As[64 * 136];
    float* Wsf = (float*)Ws;
    const int tid = threadIdx.x;
    const int bid = blockIdx.x;
    const int side = bid >= nbA;
    const short* A = side ? aggB : aggA;
    const int N = side ? NB_ : NA_;
    const int row0 = (side ? bid - nbA : bid) * 64;
    const short* Wt = Wl + (size_t)(side ? 9 : 8) * 16384;
    const float* bias = bl + (side ? 9 : 8) * 128;

    #pragma unroll
    for (int it = 0; it < 8; ++it) {
        int chunk = tid + it * 256;
        int r = chunk >> 4, c8 = (chunk & 15) * 8;
        *(int4*)&Ws[r * 136 + c8] = *(const int4*)&Wt[r * 128 + c8];
    }
    #pragma unroll
    for (int it = 0; it < 4; ++it) {
        int chunk = tid + it * 256;
        int r = chunk >> 4, c8 = (chunk & 15) * 8;
        int gr = row0 + r;
        bf16x8 s = {};
        if (gr < N) {
            s = *(const bf16x8*)&A[(size_t)gr * F + c8];
            #pragma unroll
            for (int u = 0; u < 8; ++u) s[u] = f2bf(geluf(bf2f(s[u])));
        }
        *(bf16x8*)&As[r * 136 + c8] = s;
    }
    __syncthreads();

    const int wave = tid >> 6;
    const int lane = tid & 63;
    const int m16 = lane & 15;
    const int kg = lane >> 4;
    const int arow = wave * 16 + m16;

    f32x4 acc[8] = {};
    #pragma unroll
    for (int k0 = 0; k0 < 128; k0 += 32) {
        bf16x8 a = *(const bf16x8*)&As[arow * 136 + k0 + kg * 8];
        #pragma unroll
        for (int nt = 0; nt < 8; ++nt) {
            bf16x8 b = *(const bf16x8*)&Ws[(nt * 16 + m16) * 136 + k0 + kg * 8];
            acc[nt] = __builtin_amdgcn_mfma_f32_16x16x32_bf16(a, b, acc[nt], 0, 0, 0);
        }
    }
    __syncthreads();

    #pragma unroll
    for (int nt = 0; nt < 8; ++nt)
        #pragma unroll
        for (int r = 0; r < 4; ++r)
            Wsf[(wave * 16 + kg * 4 + r) * 132 + nt * 16 + m16] = acc[nt][r];
    __syncthreads();

    float sg = 1.f / (1.f + expf(-skipp[side]));
    #pragma unroll
    for (int it = 0; it < 4; ++it) {
        int chunk = tid + it * 256;
        int r = chunk >> 4, c8 = (chunk & 15) * 8;
        int gr = row0 + r;
        if (gr >= N) continue;
        float4 b0 = *(const float4*)&bias[c8];
        float4 b1 = *(const float4*)&bias[c8 + 4];
        float v[8];
        #pragma unroll
        for (int u = 0; u < 8; ++u) v[u] = Wsf[r * 132 + c8 + u];
        v[0] += b0.x; v[1] += b0.y; v[2] += b0.z; v[3] += b0.w;
        v[4] += b1.x; v[5] += b1.y; v[6] += b1.z; v[7] += b1.w;
        const short* xb = side ? xbB : xbA;
        bf16x8 xrv = *(const bf16x8*)&xb[(size_t)gr * F + c8];
        float* Cf = side ? CfB : CfA;
        float o[8];
        #pragma unroll
        for (int u = 0; u < 8; ++u)
            o[u] = sg * v[u] + (1.f - sg) * bf2f(xrv[u]);
        *(float4*)&Cf[(size_t)gr * F + c8]     = make_float4(o[0], o[1], o[2], o[3]);
        *(float4*)&Cf[(size_t)gr * F + c8 + 4] = make_float4(o[4], o[5], o[6], o[7]);
    }
}

// ---------------- combined CSR build ----------------------------------------

__global__ void hist_all(const int* __restrict__ ei0, const int* __restrict__ ei1,
                         const int* __restrict__ ei2, int E0, int E1, int E2,
                         int NB_, int NA_, int* __restrict__ cnt) {
    int i = blockIdx.x * 256 + threadIdx.x;
    if (i >= E0 + E1 + E2) return;
    const int* ei; int li, Ee, base;
    if (i < E0)           { li = i;           ei = ei0; Ee = E0; base = 0; }
    else if (i < E0 + E1) { li = i - E0;      ei = ei1; Ee = E1; base = NB_; }
    else                  { li = i - E0 - E1; ei = ei2; Ee = E2; base = NB_ + NA_; }
    atomicAdd(&cnt[base + ei[Ee + li]], 1);
}

__global__ void scan1(const int* __restrict__ cnt, int n, int* __restrict__ off,
                      int* __restrict__ bsum) {
    __shared__ int lds[256];
    int tid = threadIdx.x, i = blockIdx.x * 256 + tid;
    int v = (i < n) ? cnt[i] : 0;
    lds[tid] = v;
    __syncthreads();
    #pragma unroll
    for (int s = 1; s < 256; s <<= 1) {
        int t = (tid >= s) ? lds[tid - s] : 0;
        __syncthreads();
        lds[tid] += t;
        __syncthreads();
    }
    if (i < n) off[i] = lds[tid] - v;
    if (tid == 255) bsum[blockIdx.x] = lds[255];
}

__global__ __launch_bounds__(1024) void scan2(int* __restrict__ bsum, int nb,
                                              int* __restrict__ off_n) {
    __shared__ int lds[1024];
    int tid = threadIdx.x;
    int v = (tid < nb) ? bsum[tid] : 0;
    lds[tid] = v;
    __syncthreads();
    #pragma unroll
    for (int s = 1; s < 1024; s <<= 1) {
        int t = (tid >= s) ? lds[tid - s] : 0;
        __syncthreads();
        lds[tid] += t;
        __syncthreads();
    }
    if (tid < nb) bsum[tid] = lds[tid] - v;
    if (tid == 1023) *off_n = lds[1023];
}

__global__ void scan3(int* __restrict__ off, int* __restrict__ woff,
                      const int* __restrict__ bsum, int n) {
    int i = blockIdx.x * 256 + threadIdx.x;
    if (i < n) {
        int v = off[i] + bsum[blockIdx.x];
        off[i] = v;
        woff[i] = v;
    }
}

// stores PRE-SCALED src offsets (src * 16 = uint4 row offset of [N][128] bf16)
__global__ void scatter_all(const int* __restrict__ ei0, const int* __restrict__ ei1,
                            const int* __restrict__ ei2, int E0, int E1, int E2,
                            int NB_, int NA_, int* __restrict__ woff,
                            int* __restrict__ csr_src) {
    int i = blockIdx.x * 256 + threadIdx.x;
    if (i >= E0 + E1 + E2) return;
    const int* ei; int li, Ee, base;
    if (i < E0)           { li = i;           ei = ei0; Ee = E0; base = 0; }
    else if (i < E0 + E1) { li = i - E0;      ei = ei1; Ee = E1; base = NB_; }
    else                  { li = i - E0 - E1; ei = ei2; Ee = E2; base = NB_ + NA_; }
    int p = atomicAdd(&woff[base + ei[Ee + li]], 1);
    csr_src[p] = ei[li] * 16;
}

// ---- fused segment attention: 4 edge slots x 16 lanes, lane-local dot -----
// lane l: slot s=l>>4, pos p=l&15 (16B of the 256B row), head h=p>>1.
__device__ __forceinline__ void seg_set4(
    const uint4* __restrict__ kArr, const uint4* __restrict__ vArr,
    int c0, int e1, const int* __restrict__ csr, int s, int p,
    const float* __restrict__ qf, float pr,
    float* __restrict__ accv, float& den) {
    for (; c0 < e1; c0 += 4) {
        int rem = e1 - c0;
        bool act = s < rem;
        int sj = csr[c0 + (act ? s : 0)];        // slot 0 always valid here
        uint4 kw = kArr[sj + p];
        uint4 vw = vArr[sj + p];
        float d = bflo(kw.x) * qf[0];
        d = fmaf(bfhi(kw.x), qf[1], d);
        d = fmaf(bflo(kw.y), qf[2], d);
        d = fmaf(bfhi(kw.y), qf[3], d);
        d = fmaf(bflo(kw.z), qf[4], d);
        d = fmaf(bfhi(kw.z), qf[5], d);
        d = fmaf(bflo(kw.w), qf[6], d);
        d = fmaf(bfhi(kw.w), qf[7], d);
        d += __shfl_xor(d, 1);                   // pair completes the 16-dim head
        float ex = __expf(fminf(d * pr, 80.f));
        ex = act ? ex : 0.f;
        den += ex;
        accv[0] = fmaf(ex, bflo(vw.x), accv[0]);
        accv[1] = fmaf(ex, bfhi(vw.x), accv[1]);
        accv[2] = fmaf(ex, bflo(vw.y), accv[2]);
        accv[3] = fmaf(ex, bfhi(vw.y), accv[3]);
        accv[4] = fmaf(ex, bflo(vw.z), accv[4]);
        accv[5] = fmaf(ex, bfhi(vw.z), accv[5]);
        accv[6] = fmaf(ex, bflo(vw.w), accv[6]);
        accv[7] = fmaf(ex, bfhi(vw.w), accv[7]);
    }
}

__device__ __forceinline__ void seg_fold(float* __restrict__ accv, float& den,
                                         float* __restrict__ r) {
    #pragma unroll
    for (int j = 0; j < 8; ++j) {
        accv[j] += __shfl_xor(accv[j], 16);
        accv[j] += __shfl_xor(accv[j], 32);
    }
    den += __shfl_xor(den, 16);
    den += __shfl_xor(den, 32);
    float inv = 1.f / (den + 1e-16f);
    #pragma unroll
    for (int j = 0; j < 8; ++j) r[j] = fmaf(accv[j], inv, r[j]);
}

__global__ __launch_bounds__(256) void seg_attn_all(
    const short* __restrict__ qA, const short* __restrict__ kA0,
    const short* __restrict__ vA0, const short* __restrict__ kA2,
    const short* __restrict__ vA2, const short* __restrict__ qB,
    const short* __restrict__ kB1, const short* __restrict__ vB1,
    const int* __restrict__ off0, const int* __restrict__ off1,
    const int* __restrict__ off2, const int* __restrict__ csrS,
    const float* __restrict__ prelL,
    short* __restrict__ aggA, short* __restrict__ aggB,
    int NA_, int NB_, int nba) {
    const int wv = threadIdx.x >> 6;
    const int l = threadIdx.x & 63;
    const int s = l >> 4;
    const int p = l & 15;
    const int h = p >> 1;
    const int isA = (int)blockIdx.x < nba;
    int dst = (isA ? blockIdx.x : blockIdx.x - nba) * 4 + wv;
    if (dst >= (isA ? NA_ : NB_)) return;

    uint4 qw = ((const uint4*)(isA ? qA : qB))[(size_t)dst * 16 + p];
    float qf[8] = {bflo(qw.x), bfhi(qw.x), bflo(qw.y), bfhi(qw.y),
                   bflo(qw.z), bfhi(qw.z), bflo(qw.w), bfhi(qw.w)};

    float r[8] = {};
    float accv[8] = {};
    float den = 0.f;
    if (isA) {
        seg_set4((const uint4*)kB1, (const uint4*)vB1, off1[dst], off1[dst + 1],
                 csrS, s, p, qf, prelL[1 * NH + h] * 0.25f, accv, den);
        seg_fold(accv, den, r);
        #pragma unroll
        for (int j = 0; j < 8; ++j) accv[j] = 0.f;
        den = 0.f;
        seg_set4((const uint4*)kA2, (const uint4*)vA2, off2[dst], off2[dst + 1],
                 csrS, s, p, qf, prelL[2 * NH + h] * 0.25f, accv, den);
        seg_fold(accv, den, r);
    } else {
        seg_set4((const uint4*)kA0, (const uint4*)vA0, off0[dst], off0[dst + 1],
                 csrS, s, p, qf, prelL[0 * NH + h] * 0.25f, accv, den);
        seg_fold(accv, den, r);
    }
    if (s == 0) {
        uint4 o;
        o.x = packbf(r[0], r[1]);
        o.y = packbf(r[2], r[3]);
        o.z = packbf(r[4], r[5]);
        o.w = packbf(r[6], r[7]);
        ((uint4*)(isA ? aggA : aggB))[(size_t)dst * 16 + p] = o;
    }
}

extern "C" void kernel_launch(void* const* d_in, const int* in_sizes, int n_in,
                              void* d_out, int out_size, void* d_ws, size_t ws_size,
                              hipStream_t stream) {
    const float* xa   = (const float*)d_in[0];
    const float* xb   = (const float*)d_in[1];
    const int* ei_ab  = (const int*)d_in[2];
    const int* ei_ba  = (const int*)d_in[3];
    const int* ei_aa  = (const int*)d_in[4];
    const float* Wk   = (const float*)d_in[5];
    const float* bk   = (const float*)d_in[6];
    const float* Wq   = (const float*)d_in[7];
    const float* bq   = (const float*)d_in[8];
    const float* Wv   = (const float*)d_in[9];
    const float* bv   = (const float*)d_in[10];
    const float* Wa   = (const float*)d_in[11];
    const float* ba   = (const float*)d_in[12];
    const float* skip = (const float*)d_in[13];
    const float* arel = (const float*)d_in[14];
    const float* mrel = (const float*)d_in[15];
    const float* prel = (const float*)d_in[16];

    const int NA = in_sizes[0] / F;
    const int NB = in_sizes[1] / F;
    const int E0 = in_sizes[2] / 2, E1 = in_sizes[3] / 2, E2 = in_sizes[4] / 2;
    const int ET = E0 + E1 + E2;
    const int NT = NB + NA + NA;   // combined dst space: e0 | e1 | e2

    float* ws = (float*)d_ws;
    size_t o = 0;
    float* bslots = ws + o; o += 2 * 10 * 128;
    // ints
    int* iws = (int*)(ws + o);
    size_t io = 0;
    int* cnt   = iws + io; io += NT;
    int* bsum  = iws + io; io += 1024;
    int* offc  = iws + io; io += NT + 1;
    int* woff  = iws + io; io += NT;
    int* csrS  = iws + io; io += ET;
    io = (io + 7) & ~(size_t)7;
    // shorts (bf16), all [N][128], 16B-aligned
    short* sws = (short*)(iws + io);
    size_t so = 0;
    short* qA  = sws + so; so += (size_t)NA * 128;
    short* kA0 = sws + so; so += (size_t)NA * 128;
    short* vA0 = sws + so; so += (size_t)NA * 128;
    short* kA2 = sws + so; so += (size_t)NA * 128;
    short* vA2 = sws + so; so += (size_t)NA * 128;
    short* qB  = sws + so; so += (size_t)NB * 128;
    short* kB1 = sws + so; so += (size_t)NB * 128;
    short* vB1 = sws + so; so += (size_t)NB * 128;
    short* aggA = sws + so; so += (size_t)NA * 128;
    short* aggB = sws + so; so += (size_t)NB * 128;
    short* x1ab = sws + so; so += (size_t)NA * 128;
    short* x1bb = sws + so; so += (size_t)NB * 128;
    short* Wslots = sws + so; so += (size_t)2 * 10 * 16384;

    float* outA = (float*)d_out;
    float* outB = (float*)d_out + (size_t)NA * F;

    // ---- weights for both layers ----
    {
        dim3 g(cdiv(10 * 16384 + 10 * 128, 256), 2);
        prep_weights<<<g, 256, 0, stream>>>(Wk, bk, Wq, bq, Wv, bv, Wa, ba,
                                            arel, mrel, Wslots, bslots);
    }

    // ---- combined CSR ----
    hipMemsetAsync(cnt, 0, (size_t)NT * sizeof(int), stream);
    hist_all<<<cdiv(ET, 256), 256, 0, stream>>>(ei_ab, ei_ba, ei_aa, E0, E1, E2, NB, NA, cnt);
    {
        int nb = cdiv(NT, 256);
        scan1<<<nb, 256, 0, stream>>>(cnt, NT, offc, bsum);
        scan2<<<1, 1024, 0, stream>>>(bsum, nb, offc + NT);
        scan3<<<nb, 256, 0, stream>>>(offc, woff, bsum, NT);
    }
    scatter_all<<<cdiv(ET, 256), 256, 0, stream>>>(ei_ab, ei_ba, ei_aa, E0, E1, E2, NB, NA, woff, csrS);

    const int* off_e0 = offc;
    const int* off_e1 = offc + NB;
    const int* off_e2 = offc + NB + NA;

    const int nbA64 = cdiv(NA, 64), nbB64 = cdiv(NB, 64);
    const int nba4 = cdiv(NA, 4), nbb4 = cdiv(NB, 4);

    const short* Wl0 = Wslots;
    const short* Wl1 = Wslots + (size_t)10 * 16384;
    const float* bl0 = bslots;
    const float* bl1 = bslots + 10 * 128;

    // layer 0 QKV
    gemm_qkv_all<<<nbA64 + nbB64, 256, 0, stream>>>(
        xa, xb, Wl0, bl0, qA, kA0, vA0, kA2, vA2, qB, kB1, vB1, NA, NB, nbA64);

    // layer 0 attention
    seg_attn_all<<<nba4 + nbb4, 256, 0, stream>>>(
        qA, kA0, vA0, kA2, vA2, qB, kB1, vB1,
        off_e0, off_e1, off_e2, csrS, prel, aggA, aggB, NA, NB, nba4);

    // fused: layer-0 out-projection + layer-1 QKV
    fused_out_qkv<<<nbA64 + nbB64, 256, 0, stream>>>(
        aggA, aggB, Wl0, bl0, xa, xb, skip, Wl1, bl1,
        x1ab, x1bb, qA, kA0, vA0, kA2, vA2, qB, kB1, vB1, NA, NB, nbA64);

    // layer 1 attention
    seg_attn_all<<<nba4 + nbb4, 256, 0, stream>>>(
        qA, kA0, vA0, kA2, vA2, qB, kB1, vB1,
        off_e0, off_e1, off_e2, csrS, prel + 3 * NH, aggA, aggB, NA, NB, nba4);

    // final out-projection
    gemm_out_final<<<nbA64 + nbB64, 256, 0, stream>>>(
        aggA, aggB, Wl1, bl1, x1ab, x1bb, skip + 2, outA, outB, NA, NB, nbA64);
}

// Round 11
// 335.691 us; speedup vs baseline: 1.2551x; 1.0165x over previous
//
#include <hip/hip_runtime.h>
#include <hip/hip_bf16.h>
#include <math.h>

#define F 128
#define NH 8
#define HD 16

static inline int cdiv(int a, int b) { return (a + b - 1) / b; }

typedef __attribute__((ext_vector_type(8))) short bf16x8;
typedef __attribute__((ext_vector_type(4))) float f32x4;

__device__ __forceinline__ float geluf(float x) {
    return 0.5f * x * (1.f + erff(x * 0.70710678118654752440f));
}

__device__ __forceinline__ short f2bf(float f) {
    __hip_bfloat16 h = __float2bfloat16(f);
    return *reinterpret_cast<short*>(&h);
}

__device__ __forceinline__ float bflo(unsigned int u) { return __uint_as_float(u << 16); }
__device__ __forceinline__ float bfhi(unsigned int u) { return __uint_as_float(u & 0xffff0000u); }
__device__ __forceinline__ float bf2f(short s) {
    return __uint_as_float(((unsigned int)(unsigned short)s) << 16);
}
__device__ __forceinline__ unsigned int packbf(float a, float b) {
    return (unsigned int)(unsigned short)f2bf(a) | ((unsigned int)(unsigned short)f2bf(b) << 16);
}

// async global->LDS, 16B per lane; LDS dest = wave-uniform base + lane*16
__device__ __forceinline__ void glds16(const void* g, void* l) {
    __builtin_amdgcn_global_load_lds(
        (const __attribute__((address_space(1))) unsigned int*)g,
        (__attribute__((address_space(3))) unsigned int*)l, 16, 0, 0);
}

// ---- weight prep ----------------------------------------------------------
// W slots stored SWIZZLED: 16B chunk c of row n lives at chunk (c + (n&15))&15.
// LDS staging is then a linear copy (global_load_lds) and the B-fragment read
// applies the same rotation -> bank-conflict-free without padding.
// slot: 0 q(t0) | 1 k-fused e0 | 2 v-fused e0 | 3 k-fused e2 | 4 v-fused e2
//       5 q(t1) | 6 k-fused e1 | 7 v-fused e1 | 8 a(t0) | 9 a(t1)
__device__ __forceinline__ void slot_info(int slot, int& kind, int& wsel, int& e, int& t) {
    switch (slot) {
        case 0: kind = 0; wsel = 0; t = 0; e = 0; break;
        case 1: kind = 1; wsel = 1; t = 0; e = 0; break;
        case 2: kind = 1; wsel = 2; t = 0; e = 0; break;
        case 3: kind = 1; wsel = 1; t = 0; e = 2; break;
        case 4: kind = 1; wsel = 2; t = 0; e = 2; break;
        case 5: kind = 0; wsel = 0; t = 1; e = 0; break;
        case 6: kind = 1; wsel = 1; t = 1; e = 1; break;
        case 7: kind = 1; wsel = 2; t = 1; e = 1; break;
        case 8: kind = 0; wsel = 3; t = 0; e = 0; break;
        default: kind = 0; wsel = 3; t = 1; e = 0; break;
    }
}

__global__ void prep_weights(const float* __restrict__ Wk, const float* __restrict__ bk,
                             const float* __restrict__ Wq, const float* __restrict__ bq,
                             const float* __restrict__ Wv, const float* __restrict__ bv,
                             const float* __restrict__ Wa, const float* __restrict__ ba,
                             const float* __restrict__ arel, const float* __restrict__ mrel,
                             short* __restrict__ Wslots, float* __restrict__ bslots) {
    const int WTOT = 10 * 16384;
    const int layer = blockIdx.y;
    short* Wl = Wslots + (size_t)layer * WTOT;
    float* bl = bslots + (size_t)layer * 10 * 128;
    int idx = blockIdx.x * blockDim.x + threadIdx.x;
    if (idx < WTOT) {
        int slot = idx >> 14, rem = idx & 16383;
        int n = rem >> 7, k = rem & 127;
        int kind, wsel, e, t;
        slot_info(slot, kind, wsel, e, t);
        float out;
        if (kind == 0) {
            const float* Wb = (wsel == 0 ? Wq : Wa) + (size_t)(layer * 2 + t) * 16384;
            out = Wb[k * 128 + n];
        } else {
            int h = n >> 4, j = n & 15;
            const float* Wb = (wsel == 1 ? Wk : Wv) + (size_t)(layer * 2 + t) * 16384;
            const float* R = (wsel == 1 ? arel : mrel) + (size_t)((layer * 3 + e) * NH + h) * 256;
            float s = 0.f;
            #pragma unroll
            for (int d = 0; d < HD; ++d) s += Wb[k * 128 + h * 16 + d] * R[d * 16 + j];
            out = s;
        }
        int chunk = k >> 3, kin = k & 7;
        int cph = (chunk + (n & 15)) & 15;
        Wl[(size_t)slot * 16384 + n * 128 + cph * 8 + kin] = f2bf(out);
    } else {
        int r = idx - WTOT;
        if (r < 10 * 128) {
            int slot = r >> 7, n = r & 127;
            int kind, wsel, e, t;
            slot_info(slot, kind, wsel, e, t);
            float out;
            if (kind == 0) {
                const float* bb = (wsel == 0 ? bq : ba) + (size_t)(layer * 2 + t) * 128;
                out = bb[n];
            } else {
                int h = n >> 4, j = n & 15;
                const float* bb = (wsel == 1 ? bk : bv) + (size_t)(layer * 2 + t) * 128;
                const float* R = (wsel == 1 ? arel : mrel) + (size_t)((layer * 3 + e) * NH + h) * 256;
                float s = 0.f;
                #pragma unroll
                for (int d = 0; d < HD; ++d) s += bb[h * 16 + d] * R[d * 16 + j];
                out = s;
            }
            bl[slot * 128 + n] = out;
        }
    }
}

// helper: slot -> output pointer for qkv stores (all [N][128] bf16)
__device__ __forceinline__ short* qkv_slot_ptr(int side, int s,
    short* qA, short* kA0, short* vA0, short* kA2, short* vA2,
    short* qB, short* kB1, short* vB1) {
    if (side) {
        if (s == 0) return qB;
        if (s == 1) return kB1;
        return vB1;
    }
    if (s == 0) return qA;
    if (s == 1) return kA0;
    if (s == 2) return vA0;
    if (s == 3) return kA2;
    return vA2;
}

// stage a 32KB (pre-swizzled) weight matrix into linear LDS via global_load_lds
__device__ __forceinline__ void stage_W(const short* __restrict__ Wt, short* Ws,
                                        int wave, int lane) {
    #pragma unroll
    for (int it = 0; it < 8; ++it) {
        int off = (it * 4 + wave) * 1024;      // bytes, wave-uniform
        glds16((const char*)Wt + off + lane * 16, (char*)Ws + off);
    }
}

// ---- layer-0 QKV: f32 input, slot-looped, glds W staging ------------------
__global__ __launch_bounds__(256) void gemm_qkv_all(
    const float* __restrict__ Aa, const float* __restrict__ Ab,
    const short* __restrict__ Wl, const float* __restrict__ bl,
    short* __restrict__ qA, short* __restrict__ kA0, short* __restrict__ vA0,
    short* __restrict__ kA2, short* __restrict__ vA2,
    short* __restrict__ qB, short* __restrict__ kB1, short* __restrict__ vB1,
    int NA_, int NB_, int nbA) {
    __shared__ __align__(16) float Wsf[64 * 132];   // aliases Ws (33792 >= 32768)
    __shared__ __align__(16) short As[64 * 136];
    short* Ws = (short*)Wsf;
    const int tid = threadIdx.x;
    const int bid = blockIdx.x;
    const int side = bid >= nbA;
    const float* A = side ? Ab : Aa;
    const int N = side ? NB_ : NA_;
    const int row0 = (side ? bid - nbA : bid) * 64;
    const short* Wbase = Wl + (side ? (size_t)5 * 16384 : 0);
    const float* bbase = bl + (side ? 5 * 128 : 0);
    const int S = side ? 3 : 5;

    const int wave = tid >> 6;
    const int lane = tid & 63;
    const int m16 = lane & 15;
    const int kg = lane >> 4;
    const int arow = wave * 16 + m16;

    #pragma unroll
    for (int it = 0; it < 4; ++it) {
        int chunk = tid + it * 256;
        int r = chunk >> 4, c8 = (chunk & 15) * 8;
        int gr = row0 + r;
        bf16x8 s = {};
        if (gr < N) {
            float4 v0 = *(const float4*)&A[(size_t)gr * F + c8];
            float4 v1 = *(const float4*)&A[(size_t)gr * F + c8 + 4];
            s[0] = f2bf(v0.x); s[1] = f2bf(v0.y); s[2] = f2bf(v0.z); s[3] = f2bf(v0.w);
            s[4] = f2bf(v1.x); s[5] = f2bf(v1.y); s[6] = f2bf(v1.z); s[7] = f2bf(v1.w);
        }
        *(bf16x8*)&As[r * 136 + c8] = s;
    }
    __syncthreads();

    bf16x8 af[4];
    #pragma unroll
    for (int kq = 0; kq < 4; ++kq)
        af[kq] = *(const bf16x8*)&As[arow * 136 + kq * 32 + kg * 8];

    for (int s = 0; s < S; ++s) {
        if (s) __syncthreads();                 // prior Ws/Wsf readers done
        stage_W(Wbase + (size_t)s * 16384, Ws, wave, lane);
        __syncthreads();                        // drains glds (vmcnt 0)

        f32x4 acc[8] = {};
        #pragma unroll
        for (int kq = 0; kq < 4; ++kq) {
            #pragma unroll
            for (int nt = 0; nt < 8; ++nt) {
                int cph = (kq * 4 + kg + m16) & 15;
                bf16x8 b = *(const bf16x8*)&Ws[(nt * 16 + m16) * 128 + cph * 8];
                acc[nt] = __builtin_amdgcn_mfma_f32_16x16x32_bf16(af[kq], b, acc[nt], 0, 0, 0);
            }
        }
        __syncthreads();

        #pragma unroll
        for (int nt = 0; nt < 8; ++nt)
            #pragma unroll
            for (int r = 0; r < 4; ++r)
                Wsf[(wave * 16 + kg * 4 + r) * 132 + nt * 16 + m16] = acc[nt][r];
        __syncthreads();

        short* optr = qkv_slot_ptr(side, s, qA, kA0, vA0, kA2, vA2, qB, kB1, vB1);
        const float* bias = bbase + s * 128;
        #pragma unroll
        for (int it = 0; it < 4; ++it) {
            int chunk = tid + it * 256;
            int r = chunk >> 4, c8 = (chunk & 15) * 8;
            int gr = row0 + r;
            if (gr >= N) continue;
            float4 b0 = *(const float4*)&bias[c8];
            float4 b1 = *(const float4*)&bias[c8 + 4];
            float4 va = *(float4*)&Wsf[r * 132 + c8];
            float4 vb = *(float4*)&Wsf[r * 132 + c8 + 4];
            bf16x8 o;
            o[0] = f2bf(va.x + b0.x); o[1] = f2bf(va.y + b0.y);
            o[2] = f2bf(va.z + b0.z); o[3] = f2bf(va.w + b0.w);
            o[4] = f2bf(vb.x + b1.x); o[5] = f2bf(vb.y + b1.y);
            o[6] = f2bf(vb.z + b1.z); o[7] = f2bf(vb.w + b1.w);
            *(bf16x8*)&optr[(size_t)gr * F + c8] = o;
        }
    }
}

// ---- FUSED: layer-0 out-projection + layer-1 QKV --------------------------
__global__ __launch_bounds__(256) void fused_out_qkv(
    const short* __restrict__ aggA, const short* __restrict__ aggB,
    const short* __restrict__ Wl0, const float* __restrict__ bl0,
    const float* __restrict__ xfA, const float* __restrict__ xfB,
    const float* __restrict__ skipp,
    const short* __restrict__ Wl1, const float* __restrict__ bl1,
    short* __restrict__ x1A, short* __restrict__ x1B,
    short* __restrict__ qA, short* __restrict__ kA0, short* __restrict__ vA0,
    short* __restrict__ kA2, short* __restrict__ vA2,
    short* __restrict__ qB, short* __restrict__ kB1, short* __restrict__ vB1,
    int NA_, int NB_, int nbA) {
    __shared__ __align__(16) float Wsf[64 * 132];
    __shared__ __align__(16) short As[64 * 136];
    short* Ws = (short*)Wsf;
    const int tid = threadIdx.x;
    const int bid = blockIdx.x;
    const int side = bid >= nbA;
    const short* A = side ? aggB : aggA;
    const int N = side ? NB_ : NA_;
    const int row0 = (side ? bid - nbA : bid) * 64;
    const short* Wt0 = Wl0 + (size_t)(side ? 9 : 8) * 16384;
    const float* bias0 = bl0 + (side ? 9 : 8) * 128;

    const int wave = tid >> 6;
    const int lane = tid & 63;
    const int m16 = lane & 15;
    const int kg = lane >> 4;
    const int arow = wave * 16 + m16;

    stage_W(Wt0, Ws, wave, lane);
    #pragma unroll
    for (int it = 0; it < 4; ++it) {
        int chunk = tid + it * 256;
        int r = chunk >> 4, c8 = (chunk & 15) * 8;
        int gr = row0 + r;
        bf16x8 s = {};
        if (gr < N) {
            s = *(const bf16x8*)&A[(size_t)gr * F + c8];
            #pragma unroll
            for (int u = 0; u < 8; ++u) s[u] = f2bf(geluf(bf2f(s[u])));
        }
        *(bf16x8*)&As[r * 136 + c8] = s;
    }
    __syncthreads();

    {   // out-projection MFMA
        f32x4 acc[8] = {};
        #pragma unroll
        for (int kq = 0; kq < 4; ++kq) {
            bf16x8 a = *(const bf16x8*)&As[arow * 136 + kq * 32 + kg * 8];
            #pragma unroll
            for (int nt = 0; nt < 8; ++nt) {
                int cph = (kq * 4 + kg + m16) & 15;
                bf16x8 b = *(const bf16x8*)&Ws[(nt * 16 + m16) * 128 + cph * 8];
                acc[nt] = __builtin_amdgcn_mfma_f32_16x16x32_bf16(a, b, acc[nt], 0, 0, 0);
            }
        }
        __syncthreads();
        #pragma unroll
        for (int nt = 0; nt < 8; ++nt)
            #pragma unroll
            for (int r = 0; r < 4; ++r)
                Wsf[(wave * 16 + kg * 4 + r) * 132 + nt * 16 + m16] = acc[nt][r];
        __syncthreads();
    }

    {   // epilogue: x1 = relu(skip-gate); store global bf16 AND write into As
        float sg = 1.f / (1.f + expf(-skipp[side]));
        short* x1 = side ? x1B : x1A;
        const float* xf = side ? xfB : xfA;
        #pragma unroll
        for (int it = 0; it < 4; ++it) {
            int chunk = tid + it * 256;
            int r = chunk >> 4, c8 = (chunk & 15) * 8;
            int gr = row0 + r;
            if (gr >= N) continue;
            float4 b0 = *(const float4*)&bias0[c8];
            float4 b1 = *(const float4*)&bias0[c8 + 4];
            float4 va = *(float4*)&Wsf[r * 132 + c8];
            float4 vb = *(float4*)&Wsf[r * 132 + c8 + 4];
            float4 x0v = *(const float4*)&xf[(size_t)gr * F + c8];
            float4 x1v = *(const float4*)&xf[(size_t)gr * F + c8 + 4];
            float v[8] = {va.x + b0.x, va.y + b0.y, va.z + b0.z, va.w + b0.w,
                          vb.x + b1.x, vb.y + b1.y, vb.z + b1.z, vb.w + b1.w};
            float xr[8] = {x0v.x, x0v.y, x0v.z, x0v.w, x1v.x, x1v.y, x1v.z, x1v.w};
            bf16x8 o;
            #pragma unroll
            for (int u = 0; u < 8; ++u)
                o[u] = f2bf(fmaxf(sg * v[u] + (1.f - sg) * xr[u], 0.f));
            *(bf16x8*)&x1[(size_t)gr * F + c8] = o;
            *(bf16x8*)&As[r * 136 + c8] = o;
        }
    }
    __syncthreads();

    // layer-1 QKV from LDS-resident x1
    bf16x8 af[4];
    #pragma unroll
    for (int kq = 0; kq < 4; ++kq)
        af[kq] = *(const bf16x8*)&As[arow * 136 + kq * 32 + kg * 8];

    const short* Wbase = Wl1 + (side ? (size_t)5 * 16384 : 0);
    const float* bbase = bl1 + (side ? 5 * 128 : 0);
    const int S = side ? 3 : 5;

    for (int s = 0; s < S; ++s) {
        __syncthreads();
        stage_W(Wbase + (size_t)s * 16384, Ws, wave, lane);
        __syncthreads();

        f32x4 acc[8] = {};
        #pragma unroll
        for (int kq = 0; kq < 4; ++kq) {
            #pragma unroll
            for (int nt = 0; nt < 8; ++nt) {
                int cph = (kq * 4 + kg + m16) & 15;
                bf16x8 b = *(const bf16x8*)&Ws[(nt * 16 + m16) * 128 + cph * 8];
                acc[nt] = __builtin_amdgcn_mfma_f32_16x16x32_bf16(af[kq], b, acc[nt], 0, 0, 0);
            }
        }
        __syncthreads();

        #pragma unroll
        for (int nt = 0; nt < 8; ++nt)
            #pragma unroll
            for (int r = 0; r < 4; ++r)
                Wsf[(wave * 16 + kg * 4 + r) * 132 + nt * 16 + m16] = acc[nt][r];
        __syncthreads();

        short* optr = qkv_slot_ptr(side, s, qA, kA0, vA0, kA2, vA2, qB, kB1, vB1);
        const float* bias = bbase + s * 128;
        #pragma unroll
        for (int it = 0; it < 4; ++it) {
            int chunk = tid + it * 256;
            int r = chunk >> 4, c8 = (chunk & 15) * 8;
            int gr = row0 + r;
            if (gr >= N) continue;
            float4 b0 = *(const float4*)&bias[c8];
            float4 b1 = *(const float4*)&bias[c8 + 4];
            float4 va = *(float4*)&Wsf[r * 132 + c8];
            float4 vb = *(float4*)&Wsf[r * 132 + c8 + 4];
            bf16x8 o;
            o[0] = f2bf(va.x + b0.x); o[1] = f2bf(va.y + b0.y);
            o[2] = f2bf(va.z + b0.z); o[3] = f2bf(va.w + b0.w);
            o[4] = f2bf(vb.x + b1.x); o[5] = f2bf(vb.y + b1.y);
            o[6] = f2bf(vb.z + b1.z); o[7] = f2bf(vb.w + b1.w);
            *(bf16x8*)&optr[(size_t)gr * F + c8] = o;
        }
    }
}

// ---- final out-projection (layer 1): bf16 residual, f32 output ------------
__global__ __launch_bounds__(256) void gemm_out_final(
    const short* __restrict__ aggA, const short* __restrict__ aggB,
    const short* __restrict__ Wl, const float* __restrict__ bl,
    const short* __restrict__ xbA, const short* __restrict__ xbB,
    const float* __restrict__ skipp,
    float* __restrict__ CfA, float* __restrict__ CfB,
    int NA_, int NB_, int nbA) {
    __shared__ __align__(16) float Wsf[64 * 132];
    __shared__ __align__(16) short As[64 * 136];
    short* Ws = (short*)Wsf;
    const int tid = threadIdx.x;
    const int bid = blockIdx.x;
    const int side = bid >= nbA;
    const short* A = side ? aggB : aggA;
    const int N = side ? NB_ : NA_;
    const int row0 = (side ? bid - nbA : bid) * 64;
    const short* Wt = Wl + (size_t)(side ? 9 : 8) * 16384;
    const float* bias = bl + (side ? 9 : 8) * 128;

    const int wave = tid >> 6;
    const int lane = tid & 63;
    const int m16 = lane & 15;
    const int kg = lane >> 4;
    const int arow = wave * 16 + m16;

    stage_W(Wt, Ws, wave, lane);
    #pragma unroll
    for (int it = 0; it < 4; ++it) {
        int chunk = tid + it * 256;
        int r = chunk >> 4, c8 = (chunk & 15) * 8;
        int gr = row0 + r;
        bf16x8 s = {};
        if (gr < N) {
            s = *(const bf16x8*)&A[(size_t)gr * F + c8];
            #pragma unroll
            for (int u = 0; u < 8; ++u) s[u] = f2bf(geluf(bf2f(s[u])));
        }
        *(bf16x8*)&As[r * 136 + c8] = s;
    }
    __syncthreads();

    f32x4 acc[8] = {};
    #pragma unroll
    for (int kq = 0; kq < 4; ++kq) {
        bf16x8 a = *(const bf16x8*)&As[arow * 136 + kq * 32 + kg * 8];
        #pragma unroll
        for (int nt = 0; nt < 8; ++nt) {
            int cph = (kq * 4 + kg + m16) & 15;
            bf16x8 b = *(const bf16x8*)&Ws[(nt * 16 + m16) * 128 + cph * 8];
            acc[nt] = __builtin_amdgcn_mfma_f32_16x16x32_bf16(a, b, acc[nt], 0, 0, 0);
        }
    }
    __syncthreads();

    #pragma unroll
    for (int nt = 0; nt < 8; ++nt)
        #pragma unroll
        for (int r = 0; r < 4; ++r)
            Wsf[(wave * 16 + kg * 4 + r) * 132 + nt * 16 + m16] = acc[nt][r];
    __syncthreads();

    float sg = 1.f / (1.f + expf(-skipp[side]));
    #pragma unroll
    for (int it = 0; it < 4; ++it) {
        int chunk = tid + it * 256;
        int r = chunk >> 4, c8 = (chunk & 15) * 8;
        int gr = row0 + r;
        if (gr >= N) continue;
        float4 b0 = *(const float4*)&bias[c8];
        float4 b1 = *(const float4*)&bias[c8 + 4];
        float4 va = *(float4*)&Wsf[r * 132 + c8];
        float4 vb = *(float4*)&Wsf[r * 132 + c8 + 4];
        float v[8] = {va.x + b0.x, va.y + b0.y, va.z + b0.z, va.w + b0.w,
                      vb.x + b1.x, vb.y + b1.y, vb.z + b1.z, vb.w + b1.w};
        const short* xb = side ? xbB : xbA;
        bf16x8 xrv = *(const bf16x8*)&xb[(size_t)gr * F + c8];
        float* Cf = side ? CfB : CfA;
        float o[8];
        #pragma unroll
        for (int u = 0; u < 8; ++u)
            o[u] = sg * v[u] + (1.f - sg) * bf2f(xrv[u]);
        *(float4*)&Cf[(size_t)gr * F + c8]     = make_float4(o[0], o[1], o[2], o[3]);
        *(float4*)&Cf[(size_t)gr * F + c8 + 4] = make_float4(o[4], o[5], o[6], o[7]);
    }
}

// ---------------- combined CSR build ----------------------------------------

__global__ void hist_all(const int* __restrict__ ei0, const int* __restrict__ ei1,
                         const int* __restrict__ ei2, int E0, int E1, int E2,
                         int NB_, int NA_, int* __restrict__ cnt) {
    int i = blockIdx.x * 256 + threadIdx.x;
    if (i >= E0 + E1 + E2) return;
    const int* ei; int li, Ee, base;
    if (i < E0)           { li = i;           ei = ei0; Ee = E0; base = 0; }
    else if (i < E0 + E1) { li = i - E0;      ei = ei1; Ee = E1; base = NB_; }
    else                  { li = i - E0 - E1; ei = ei2; Ee = E2; base = NB_ + NA_; }
    atomicAdd(&cnt[base + ei[Ee + li]], 1);
}

__global__ void scan1(const int* __restrict__ cnt, int n, int* __restrict__ off,
                      int* __restrict__ bsum) {
    __shared__ int lds[256];
    int tid = threadIdx.x, i = blockIdx.x * 256 + tid;
    int v = (i < n) ? cnt[i] : 0;
    lds[tid] = v;
    __syncthreads();
    #pragma unroll
    for (int s = 1; s < 256; s <<= 1) {
        int t = (tid >= s) ? lds[tid - s] : 0;
        __syncthreads();
        lds[tid] += t;
        __syncthreads();
    }
    if (i < n) off[i] = lds[tid] - v;
    if (tid == 255) bsum[blockIdx.x] = lds[255];
}

__global__ __launch_bounds__(1024) void scan2(int* __restrict__ bsum, int nb,
                                              int* __restrict__ off_n) {
    __shared__ int lds[1024];
    int tid = threadIdx.x;
    int v = (tid < nb) ? bsum[tid] : 0;
    lds[tid] = v;
    __syncthreads();
    #pragma unroll
    for (int s = 1; s < 1024; s <<= 1) {
        int t = (tid >= s) ? lds[tid - s] : 0;
        __syncthreads();
        lds[tid] += t;
        __syncthreads();
    }
    if (tid < nb) bsum[tid] = lds[tid] - v;
    if (tid == 1023) *off_n = lds[1023];
}

__global__ void scan3(int* __restrict__ off, int* __restrict__ woff,
                      const int* __restrict__ bsum, int n) {
    int i = blockIdx.x * 256 + threadIdx.x;
    if (i < n) {
        int v = off[i] + bsum[blockIdx.x];
        off[i] = v;
        woff[i] = v;
    }
}

// stores PRE-SCALED src offsets (src * 16 = uint4 row offset of [N][128] bf16)
__global__ void scatter_all(const int* __restrict__ ei0, const int* __restrict__ ei1,
                            const int* __restrict__ ei2, int E0, int E1, int E2,
                            int NB_, int NA_, int* __restrict__ woff,
                            int* __restrict__ csr_src) {
    int i = blockIdx.x * 256 + threadIdx.x;
    if (i >= E0 + E1 + E2) return;
    const int* ei; int li, Ee, base;
    if (i < E0)           { li = i;           ei = ei0; Ee = E0; base = 0; }
    else if (i < E0 + E1) { li = i - E0;      ei = ei1; Ee = E1; base = NB_; }
    else                  { li = i - E0 - E1; ei = ei2; Ee = E2; base = NB_ + NA_; }
    int p = atomicAdd(&woff[base + ei[Ee + li]], 1);
    csr_src[p] = ei[li] * 16;
}

// ---- fused segment attention: 4 edge slots x 16 lanes, lane-local dot -----
__device__ __forceinline__ void seg_set4(
    const uint4* __restrict__ kArr, const uint4* __restrict__ vArr,
    int c0, int e1, const int* __restrict__ csr, int s, int p,
    const float* __restrict__ qf, float pr,
    float* __restrict__ accv, float& den) {
    for (; c0 < e1; c0 += 4) {
        int rem = e1 - c0;
        bool act = s < rem;
        int sj = csr[c0 + (act ? s : 0)];
        uint4 kw = kArr[sj + p];
        uint4 vw = vArr[sj + p];
        float d = bflo(kw.x) * qf[0];
        d = fmaf(bfhi(kw.x), qf[1], d);
        d = fmaf(bflo(kw.y), qf[2], d);
        d = fmaf(bfhi(kw.y), qf[3], d);
        d = fmaf(bflo(kw.z), qf[4], d);
        d = fmaf(bfhi(kw.z), qf[5], d);
        d = fmaf(bflo(kw.w), qf[6], d);
        d = fmaf(bfhi(kw.w), qf[7], d);
        d += __shfl_xor(d, 1);
        float ex = __expf(fminf(d * pr, 80.f));
        ex = act ? ex : 0.f;
        den += ex;
        accv[0] = fmaf(ex, bflo(vw.x), accv[0]);
        accv[1] = fmaf(ex, bfhi(vw.x), accv[1]);
        accv[2] = fmaf(ex, bflo(vw.y), accv[2]);
        accv[3] = fmaf(ex, bfhi(vw.y), accv[3]);
        accv[4] = fmaf(ex, bflo(vw.z), accv[4]);
        accv[5] = fmaf(ex, bfhi(vw.z), accv[5]);
        accv[6] = fmaf(ex, bflo(vw.w), accv[6]);
        accv[7] = fmaf(ex, bfhi(vw.w), accv[7]);
    }
}

__device__ __forceinline__ void seg_fold(float* __restrict__ accv, float& den,
                                         float* __restrict__ r) {
    #pragma unroll
    for (int j = 0; j < 8; ++j) {
        accv[j] += __shfl_xor(accv[j], 16);
        accv[j] += __shfl_xor(accv[j], 32);
    }
    den += __shfl_xor(den, 16);
    den += __shfl_xor(den, 32);
    float inv = 1.f / (den + 1e-16f);
    #pragma unroll
    for (int j = 0; j < 8; ++j) r[j] = fmaf(accv[j], inv, r[j]);
}

__global__ __launch_bounds__(256) void seg_attn_all(
    const short* __restrict__ qA, const short* __restrict__ kA0,
    const short* __restrict__ vA0, const short* __restrict__ kA2,
    const short* __restrict__ vA2, const short* __restrict__ qB,
    const short* __restrict__ kB1, const short* __restrict__ vB1,
    const int* __restrict__ off0, const int* __restrict__ off1,
    const int* __restrict__ off2, const int* __restrict__ csrS,
    const float* __restrict__ prelL,
    short* __restrict__ aggA, short* __restrict__ aggB,
    int NA_, int NB_, int nba) {
    const int wv = threadIdx.x >> 6;
    const int l = threadIdx.x & 63;
    const int s = l >> 4;
    const int p = l & 15;
    const int h = p >> 1;
    const int isA = (int)blockIdx.x < nba;
    int dst = (isA ? blockIdx.x : blockIdx.x - nba) * 4 + wv;
    if (dst >= (isA ? NA_ : NB_)) return;

    uint4 qw = ((const uint4*)(isA ? qA : qB))[(size_t)dst * 16 + p];
    float qf[8] = {bflo(qw.x), bfhi(qw.x), bflo(qw.y), bfhi(qw.y),
                   bflo(qw.z), bfhi(qw.z), bflo(qw.w), bfhi(qw.w)};

    float r[8] = {};
    float accv[8] = {};
    float den = 0.f;
    if (isA) {
        seg_set4((const uint4*)kB1, (const uint4*)vB1, off1[dst], off1[dst + 1],
                 csrS, s, p, qf, prelL[1 * NH + h] * 0.25f, accv, den);
        seg_fold(accv, den, r);
        #pragma unroll
        for (int j = 0; j < 8; ++j) accv[j] = 0.f;
        den = 0.f;
        seg_set4((const uint4*)kA2, (const uint4*)vA2, off2[dst], off2[dst + 1],
                 csrS, s, p, qf, prelL[2 * NH + h] * 0.25f, accv, den);
        seg_fold(accv, den, r);
    } else {
        seg_set4((const uint4*)kA0, (const uint4*)vA0, off0[dst], off0[dst + 1],
                 csrS, s, p, qf, prelL[0 * NH + h] * 0.25f, accv, den);
        seg_fold(accv, den, r);
    }
    if (s == 0) {
        uint4 o;
        o.x = packbf(r[0], r[1]);
        o.y = packbf(r[2], r[3]);
        o.z = packbf(r[4], r[5]);
        o.w = packbf(r[6], r[7]);
        ((uint4*)(isA ? aggA : aggB))[(size_t)dst * 16 + p] = o;
    }
}

extern "C" void kernel_launch(void* const* d_in, const int* in_sizes, int n_in,
                              void* d_out, int out_size, void* d_ws, size_t ws_size,
                              hipStream_t stream) {
    const float* xa   = (const float*)d_in[0];
    const float* xb   = (const float*)d_in[1];
    const int* ei_ab  = (const int*)d_in[2];
    const int* ei_ba  = (const int*)d_in[3];
    const int* ei_aa  = (const int*)d_in[4];
    const float* Wk   = (const float*)d_in[5];
    const float* bk   = (const float*)d_in[6];
    const float* Wq   = (const float*)d_in[7];
    const float* bq   = (const float*)d_in[8];
    const float* Wv   = (const float*)d_in[9];
    const float* bv   = (const float*)d_in[10];
    const float* Wa   = (const float*)d_in[11];
    const float* ba   = (const float*)d_in[12];
    const float* skip = (const float*)d_in[13];
    const float* arel = (const float*)d_in[14];
    const float* mrel = (const float*)d_in[15];
    const float* prel = (const float*)d_in[16];

    const int NA = in_sizes[0] / F;
    const int NB = in_sizes[1] / F;
    const int E0 = in_sizes[2] / 2, E1 = in_sizes[3] / 2, E2 = in_sizes[4] / 2;
    const int ET = E0 + E1 + E2;
    const int NT = NB + NA + NA;   // combined dst space: e0 | e1 | e2

    float* ws = (float*)d_ws;
    size_t o = 0;
    float* bslots = ws + o; o += 2 * 10 * 128;
    // ints
    int* iws = (int*)(ws + o);
    size_t io = 0;
    int* cnt   = iws + io; io += NT;
    int* bsum  = iws + io; io += 1024;
    int* offc  = iws + io; io += NT + 1;
    int* woff  = iws + io; io += NT;
    int* csrS  = iws + io; io += ET;
    io = (io + 7) & ~(size_t)7;
    // shorts (bf16), all [N][128], 16B-aligned
    short* sws = (short*)(iws + io);
    size_t so = 0;
    short* qA  = sws + so; so += (size_t)NA * 128;
    short* kA0 = sws + so; so += (size_t)NA * 128;
    short* vA0 = sws + so; so += (size_t)NA * 128;
    short* kA2 = sws + so; so += (size_t)NA * 128;
    short* vA2 = sws + so; so += (size_t)NA * 128;
    short* qB  = sws + so; so += (size_t)NB * 128;
    short* kB1 = sws + so; so += (size_t)NB * 128;
    short* vB1 = sws + so; so += (size_t)NB * 128;
    short* aggA = sws + so; so += (size_t)NA * 128;
    short* aggB = sws + so; so += (size_t)NB * 128;
    short* x1ab = sws + so; so += (size_t)NA * 128;
    short* x1bb = sws + so; so += (size_t)NB * 128;
    short* Wslots = sws + so; so += (size_t)2 * 10 * 16384;

    float* outA = (float*)d_out;
    float* outB = (float*)d_out + (size_t)NA * F;

    // ---- weights for both layers ----
    {
        dim3 g(cdiv(10 * 16384 + 10 * 128, 256), 2);
        prep_weights<<<g, 256, 0, stream>>>(Wk, bk, Wq, bq, Wv, bv, Wa, ba,
                                            arel, mrel, Wslots, bslots);
    }

    // ---- combined CSR ----
    hipMemsetAsync(cnt, 0, (size_t)NT * sizeof(int), stream);
    hist_all<<<cdiv(ET, 256), 256, 0, stream>>>(ei_ab, ei_ba, ei_aa, E0, E1, E2, NB, NA, cnt);
    {
        int nb = cdiv(NT, 256);
        scan1<<<nb, 256, 0, stream>>>(cnt, NT, offc, bsum);
        scan2<<<1, 1024, 0, stream>>>(bsum, nb, offc + NT);
        scan3<<<nb, 256, 0, stream>>>(offc, woff, bsum, NT);
    }
    scatter_all<<<cdiv(ET, 256), 256, 0, stream>>>(ei_ab, ei_ba, ei_aa, E0, E1, E2, NB, NA, woff, csrS);

    const int* off_e0 = offc;
    const int* off_e1 = offc + NB;
    const int* off_e2 = offc + NB + NA;

    const int nbA64 = cdiv(NA, 64), nbB64 = cdiv(NB, 64);
    const int nba4 = cdiv(NA, 4), nbb4 = cdiv(NB, 4);

    const short* Wl0 = Wslots;
    const short* Wl1 = Wslots + (size_t)10 * 16384;
    const float* bl0 = bslots;
    const float* bl1 = bslots + 10 * 128;

    // layer 0 QKV
    gemm_qkv_all<<<nbA64 + nbB64, 256, 0, stream>>>(
        xa, xb, Wl0, bl0, qA, kA0, vA0, kA2, vA2, qB, kB1, vB1, NA, NB, nbA64);

    // layer 0 attention
    seg_attn_all<<<nba4 + nbb4, 256, 0, stream>>>(
        qA, kA0, vA0, kA2, vA2, qB, kB1, vB1,
        off_e0, off_e1, off_e2, csrS, prel, aggA, aggB, NA, NB, nba4);

    // fused: layer-0 out-projection + layer-1 QKV
    fused_out_qkv<<<nbA64 + nbB64, 256, 0, stream>>>(
        aggA, aggB, Wl0, bl0, xa, xb, skip, Wl1, bl1,
        x1ab, x1bb, qA, kA0, vA0, kA2, vA2, qB, kB1, vB1, NA, NB, nbA64);

    // layer 1 attention
    seg_attn_all<<<nba4 + nbb4, 256, 0, stream>>>(
        qA, kA0, vA0, kA2, vA2, qB, kB1, vB1,
        off_e0, off_e1, off_e2, csrS, prel + 3 * NH, aggA, aggB, NA, NB, nba4);

    // final out-projection
    gemm_out_final<<<nbA64 + nbB64, 256, 0, stream>>>(
        aggA, aggB, Wl1, bl1, x1ab, x1bb, skip + 2, outA, outB, NA, NB, nbA64);
}